// Round 1
// baseline (1186.014 us; speedup 1.0000x reference)
//
#include <hip/hip_runtime.h>

// ---------------------------------------------------------------------------
// EMOGI ChebConv-K2 x3 : N=100000 nodes, E=800000 edges, dims 58->300->100->1
//
// Decomposition (scatter commutes with matmul since scatter is linear):
//   deg[i]  = #edges with src==i ; dinv = 1/sqrt(deg) (0 if deg==0)
//   w_e     = -dinv[src]*dinv[dst]
//   L1: p1  = scatter_dst(w * x[src])            [N,58]
//       h1  = relu(x@W10 + p1@W11 + b1)          [N,300]
//   L2: g2  = h1@W21                             [N,100]
//       p2  = scatter_dst(w * g2[src])           [N,100]
//       h2  = relu(h1@W20 + p2 + b2)             [N,100]
//   L3: a3  = h2@W30 + b3 ; g3 = h2@W31          [N]
//       p3  = scatter_dst(w * g3[src])           [N]
//       out = a3 + p3                            [N,1]
// ---------------------------------------------------------------------------

__global__ void k_degree(const int* __restrict__ src, unsigned* __restrict__ deg, int E) {
  int i = blockIdx.x * blockDim.x + threadIdx.x;
  if (i < E) atomicAdd(&deg[src[i]], 1u);
}

__global__ void k_dinv(const unsigned* __restrict__ deg, float* __restrict__ dinv, int N) {
  int i = blockIdx.x * blockDim.x + threadIdx.x;
  if (i < N) {
    unsigned d = deg[i];
    dinv[i] = d ? rsqrtf((float)d) : 0.0f;
  }
}

// one wave per edge, lane = feature (58 feats)
__global__ void k_scatter58(const int* __restrict__ src, const int* __restrict__ dst,
                            const float* __restrict__ dinv, const float* __restrict__ x,
                            float* __restrict__ p, int E) {
  int wid = (blockIdx.x * blockDim.x + threadIdx.x) >> 6;
  if (wid >= E) return;
  int lane = threadIdx.x & 63;
  int s = src[wid], d = dst[wid];
  float w = -dinv[s] * dinv[d];
  if (w != 0.0f && lane < 58)
    atomicAdd(&p[(size_t)d * 58 + lane], w * x[(size_t)s * 58 + lane]);
}

// one wave per edge, 100 feats = lane + (lane<36 ? lane+64)
__global__ void k_scatter100(const int* __restrict__ src, const int* __restrict__ dst,
                             const float* __restrict__ dinv, const float* __restrict__ g,
                             float* __restrict__ p, int E) {
  int wid = (blockIdx.x * blockDim.x + threadIdx.x) >> 6;
  if (wid >= E) return;
  int lane = threadIdx.x & 63;
  int s = src[wid], d = dst[wid];
  float w = -dinv[s] * dinv[d];
  if (w == 0.0f) return;
  atomicAdd(&p[(size_t)d * 100 + lane], w * g[(size_t)s * 100 + lane]);
  if (lane < 36)
    atomicAdd(&p[(size_t)d * 100 + 64 + lane], w * g[(size_t)s * 100 + 64 + lane]);
}

// h1 = relu(x@W10 + p1@W11 + b1). x,p1:[N,58] W:[58,300]. 8 nodes/block, 320 thr.
#define MM1_TN 8
__global__ __launch_bounds__(320) void k_mm1(
    const float* __restrict__ x, const float* __restrict__ p1,
    const float* __restrict__ W10, const float* __restrict__ W11,
    const float* __restrict__ b1, float* __restrict__ h1, int N) {
  __shared__ __align__(16) float sx[MM1_TN * 60];
  __shared__ __align__(16) float sp[MM1_TN * 60];
  int n0 = blockIdx.x * MM1_TN;
  int t = threadIdx.x;
  int nrows = min(MM1_TN, N - n0);
  for (int idx = t; idx < nrows * 58; idx += 320) {
    int n = idx / 58, k = idx - n * 58;
    sx[n * 60 + k] = x[(size_t)n0 * 58 + idx];
    sp[n * 60 + k] = p1[(size_t)n0 * 58 + idx];
  }
  __syncthreads();
  int j = t;
  if (j >= 300) return;
  float acc[MM1_TN];
  float bb = b1[j];
#pragma unroll
  for (int n = 0; n < MM1_TN; n++) acc[n] = bb;
  for (int k = 0; k < 56; k += 4) {
    float wa0 = W10[(k + 0) * 300 + j], wa1 = W10[(k + 1) * 300 + j];
    float wa2 = W10[(k + 2) * 300 + j], wa3 = W10[(k + 3) * 300 + j];
    float wb0 = W11[(k + 0) * 300 + j], wb1 = W11[(k + 1) * 300 + j];
    float wb2 = W11[(k + 2) * 300 + j], wb3 = W11[(k + 3) * 300 + j];
#pragma unroll
    for (int n = 0; n < MM1_TN; n++) {
      float4 xv = *(const float4*)&sx[n * 60 + k];
      float4 pv = *(const float4*)&sp[n * 60 + k];
      acc[n] += xv.x * wa0 + xv.y * wa1 + xv.z * wa2 + xv.w * wa3;
      acc[n] += pv.x * wb0 + pv.y * wb1 + pv.z * wb2 + pv.w * wb3;
    }
  }
  for (int k = 56; k < 58; k++) {
    float wa = W10[k * 300 + j], wb = W11[k * 300 + j];
#pragma unroll
    for (int n = 0; n < MM1_TN; n++)
      acc[n] += sx[n * 60 + k] * wa + sp[n * 60 + k] * wb;
  }
  for (int n = 0; n < nrows; n++)
    h1[(size_t)(n0 + n) * 300 + j] = fmaxf(acc[n], 0.0f);
}

// out[n,j] = act( h[n,:]@W[:,j] (+ add + bias) ). h:[N,300] W:[300,100]. 16 nodes/block.
#define MM2_TN 16
template <bool ADDBIAS>
__global__ __launch_bounds__(128) void k_mm2(
    const float* __restrict__ h, const float* __restrict__ W,
    const float* __restrict__ bias, const float* __restrict__ add,
    float* __restrict__ out, int N) {
  __shared__ __align__(16) float sh[MM2_TN * 300];
  int n0 = blockIdx.x * MM2_TN;
  int t = threadIdx.x;
  int nrows = min(MM2_TN, N - n0);
  for (int idx = t; idx < nrows * 300; idx += 128)
    sh[idx] = h[(size_t)n0 * 300 + idx];
  __syncthreads();
  if (t >= 100) return;
  float acc[MM2_TN];
#pragma unroll
  for (int n = 0; n < MM2_TN; n++) acc[n] = 0.0f;
  for (int k = 0; k < 300; k += 4) {
    float w0 = W[(k + 0) * 100 + t], w1 = W[(k + 1) * 100 + t];
    float w2 = W[(k + 2) * 100 + t], w3 = W[(k + 3) * 100 + t];
#pragma unroll
    for (int n = 0; n < MM2_TN; n++) {
      float4 hv = *(const float4*)&sh[n * 300 + k];
      acc[n] += hv.x * w0 + hv.y * w1 + hv.z * w2 + hv.w * w3;
    }
  }
  for (int n = 0; n < nrows; n++) {
    float v = acc[n];
    if (ADDBIAS) {
      v += add[(size_t)(n0 + n) * 100 + t] + bias[t];
      v = fmaxf(v, 0.0f);
    }
    out[(size_t)(n0 + n) * 100 + t] = v;
  }
}

// per-node dual dot: a3 = h2@W30 + b3 ; g3 = h2@W31. one wave per node.
__global__ void k_mm3(const float* __restrict__ h2, const float* __restrict__ W30,
                      const float* __restrict__ W31, const float* __restrict__ b3,
                      float* __restrict__ a3, float* __restrict__ g3, int N) {
  int wid = (blockIdx.x * blockDim.x + threadIdx.x) >> 6;
  if (wid >= N) return;
  int lane = threadIdx.x & 63;
  const float* row = h2 + (size_t)wid * 100;
  float a = 0.0f, g = 0.0f;
  for (int f = lane; f < 100; f += 64) {
    float v = row[f];
    a += v * W30[f];
    g += v * W31[f];
  }
#pragma unroll
  for (int off = 32; off > 0; off >>= 1) {
    a += __shfl_down(a, off);
    g += __shfl_down(g, off);
  }
  if (lane == 0) {
    a3[wid] = a + b3[0];
    g3[wid] = g;
  }
}

__global__ void k_scatter1f(const int* __restrict__ src, const int* __restrict__ dst,
                            const float* __restrict__ dinv, const float* __restrict__ g3,
                            float* __restrict__ p3, int E) {
  int e = blockIdx.x * blockDim.x + threadIdx.x;
  if (e >= E) return;
  int s = src[e], d = dst[e];
  float w = -dinv[s] * dinv[d];
  if (w != 0.0f) atomicAdd(&p3[d], w * g3[s]);
}

__global__ void k_addout(const float* __restrict__ a3, const float* __restrict__ p3,
                         float* __restrict__ out, int N) {
  int i = blockIdx.x * blockDim.x + threadIdx.x;
  if (i < N) out[i] = a3[i] + p3[i];
}

extern "C" void kernel_launch(void* const* d_in, const int* in_sizes, int n_in,
                              void* d_out, int out_size, void* d_ws, size_t ws_size,
                              hipStream_t stream) {
  const float* x  = (const float*)d_in[0];
  const int*   ei = (const int*)d_in[1];
  const float* W1 = (const float*)d_in[2];  // [2][58][300]
  const float* b1 = (const float*)d_in[3];
  const float* W2 = (const float*)d_in[4];  // [2][300][100]
  const float* b2 = (const float*)d_in[5];
  const float* W3 = (const float*)d_in[6];  // [2][100][1]
  const float* b3 = (const float*)d_in[7];
  float* out = (float*)d_out;

  const int N = in_sizes[0] / 58;   // 100000
  const int E = in_sizes[1] / 2;    // 800000
  const int* src = ei;
  const int* dst = ei + E;

  char* ws = (char*)d_ws;
  size_t off = 0;
  auto alloc = [&](size_t bytes) -> void* {
    void* p = ws + off;
    off += (bytes + 255) & ~(size_t)255;
    return p;
  };
  unsigned* deg = (unsigned*)alloc((size_t)N * 4);
  float* dinv = (float*)alloc((size_t)N * 4);
  float* h1 = (float*)alloc((size_t)N * 300 * 4);
  float* RA = (float*)alloc((size_t)N * 100 * 4);  // p1 -> g2 -> h2
  float* RB = (float*)alloc((size_t)N * 100 * 4);  // p2 -> (g3,a3,p3)
  float* p1 = RA;
  float* g2 = RA;
  float* h2 = RA;
  float* p2 = RB;
  float* g3 = RB;
  float* a3 = RB + N;
  float* p3 = RB + 2 * N;

  const float* W10 = W1;
  const float* W11 = W1 + 58 * 300;
  const float* W20 = W2;
  const float* W21 = W2 + 300 * 100;
  const float* W30 = W3;
  const float* W31 = W3 + 100;

  // --- degree / dinv ---
  hipMemsetAsync(deg, 0, (size_t)N * 4, stream);
  k_degree<<<(E + 255) / 256, 256, 0, stream>>>(src, deg, E);
  k_dinv<<<(N + 255) / 256, 256, 0, stream>>>(deg, dinv, N);

  // --- layer 1 ---
  hipMemsetAsync(p1, 0, (size_t)N * 58 * 4, stream);
  k_scatter58<<<(E + 3) / 4, 256, 0, stream>>>(src, dst, dinv, x, p1, E);
  k_mm1<<<(N + MM1_TN - 1) / MM1_TN, 320, 0, stream>>>(x, p1, W10, W11, b1, h1, N);

  // --- layer 2 ---
  k_mm2<false><<<(N + MM2_TN - 1) / MM2_TN, 128, 0, stream>>>(h1, W21, nullptr, nullptr, g2, N);
  hipMemsetAsync(p2, 0, (size_t)N * 100 * 4, stream);
  k_scatter100<<<(E + 3) / 4, 256, 0, stream>>>(src, dst, dinv, g2, p2, E);
  k_mm2<true><<<(N + MM2_TN - 1) / MM2_TN, 128, 0, stream>>>(h1, W20, b2, p2, h2, N);

  // --- layer 3 ---
  k_mm3<<<(N + 3) / 4, 256, 0, stream>>>(h2, W30, W31, b3, a3, g3, N);
  hipMemsetAsync(p3, 0, (size_t)N * 4, stream);
  k_scatter1f<<<(E + 255) / 256, 256, 0, stream>>>(src, dst, dinv, g3, p3, E);
  k_addout<<<(N + 255) / 256, 256, 0, stream>>>(a3, p3, out, N);
}

// Round 2
// 868.677 us; speedup vs baseline: 1.3653x; 1.3653x over previous
//
#include <hip/hip_runtime.h>

// ---------------------------------------------------------------------------
// EMOGI ChebConv-K2 x3 : N=100000 nodes, E=800000 edges, dims 58->300->100->1
//
//   deg[i]  = #edges with src==i ; dinv = 1/sqrt(deg) (0 if deg==0)
//   w_e     = -dinv[src]*dinv[dst]
//   L1: p1  = prop(x)  [N,58];  h1 = relu(x@W10 + p1@W11 + b1)   [N,300]
//   L2: g2  = h1@W21 [N,100]; p2 = prop(g2); h2 = relu(h1@W20 + p2 + b2)
//   L3: a3  = h2@W30 + b3 ; g3 = h2@W31 ; out = a3 + prop(g3)
//
// prop() is gather-based: per-call CSR bucketed by dst (count -> 2-level
// exclusive scan -> fill {src, dinv[src]}), then one wave (or thread) per
// dst node accumulates in registers and writes once. No float atomics.
// ---------------------------------------------------------------------------

__global__ void k_count(const int* __restrict__ src, const int* __restrict__ dst,
                        unsigned* __restrict__ deg, unsigned* __restrict__ cnt, int E) {
  int i = blockIdx.x * blockDim.x + threadIdx.x;
  if (i < E) {
    atomicAdd(&deg[src[i]], 1u);
    atomicAdd(&cnt[dst[i]], 1u);
  }
}

__global__ void k_dinv(const unsigned* __restrict__ deg, float* __restrict__ dinv, int N) {
  int i = blockIdx.x * blockDim.x + threadIdx.x;
  if (i < N) {
    unsigned d = deg[i];
    dinv[i] = d ? rsqrtf((float)d) : 0.0f;
  }
}

// ---- exclusive scan of cnt[N] -> rowstart[N] (+ rowstart[N]=E), 1024/block ----
__global__ __launch_bounds__(256) void k_scan1(const unsigned* __restrict__ cnt,
                                               unsigned* __restrict__ btot, int N) {
  __shared__ unsigned s[256];
  int b = blockIdx.x, t = threadIdx.x;
  int base = b * 1024;
  unsigned sum = 0;
  for (int i = t; i < 1024; i += 256) {
    int idx = base + i;
    sum += (idx < N) ? cnt[idx] : 0u;
  }
  s[t] = sum;
  __syncthreads();
  for (int off = 128; off > 0; off >>= 1) {
    if (t < off) s[t] += s[t + off];
    __syncthreads();
  }
  if (t == 0) btot[b] = s[0];
}

__global__ __launch_bounds__(256) void k_scan2(unsigned* __restrict__ btot,
                                               unsigned* __restrict__ rowstart,
                                               int NB, int N, int E) {
  __shared__ unsigned s[256];
  int t = threadIdx.x;
  s[t] = (t < NB) ? btot[t] : 0u;
  __syncthreads();
  if (t == 0) {
    unsigned acc = 0;
    for (int i = 0; i < NB; i++) { unsigned v = s[i]; s[i] = acc; acc += v; }
  }
  __syncthreads();
  if (t < NB) btot[t] = s[t];
  if (t == 0) rowstart[N] = (unsigned)E;
}

__global__ __launch_bounds__(256) void k_scan3(const unsigned* __restrict__ cnt,
                                               const unsigned* __restrict__ btot,
                                               unsigned* __restrict__ rowstart,
                                               unsigned* __restrict__ cursor, int N) {
  __shared__ unsigned ssum[256];
  int b = blockIdx.x, t = threadIdx.x;
  int base = b * 1024 + t * 4;
  unsigned v0 = 0, v1 = 0, v2 = 0, v3 = 0;
  if (base + 0 < N) v0 = cnt[base + 0];
  if (base + 1 < N) v1 = cnt[base + 1];
  if (base + 2 < N) v2 = cnt[base + 2];
  if (base + 3 < N) v3 = cnt[base + 3];
  ssum[t] = v0 + v1 + v2 + v3;
  __syncthreads();
  for (int off = 1; off < 256; off <<= 1) {
    unsigned add = (t >= off) ? ssum[t - off] : 0u;
    __syncthreads();
    ssum[t] += add;
    __syncthreads();
  }
  unsigned texcl = ((t == 0) ? 0u : ssum[t - 1]) + btot[b];
  unsigned r0 = texcl, r1 = r0 + v0, r2 = r1 + v1, r3 = r2 + v2;
  if (base + 0 < N) { rowstart[base + 0] = r0; cursor[base + 0] = r0; }
  if (base + 1 < N) { rowstart[base + 1] = r1; cursor[base + 1] = r1; }
  if (base + 2 < N) { rowstart[base + 2] = r2; cursor[base + 2] = r2; }
  if (base + 3 < N) { rowstart[base + 3] = r3; cursor[base + 3] = r3; }
}

// er[pos] = {src, dinv[src]} bucketed by dst
__global__ void k_fill(const int* __restrict__ src, const int* __restrict__ dst,
                       const float* __restrict__ dinv, unsigned* __restrict__ cursor,
                       int2* __restrict__ er, int E) {
  int e = blockIdx.x * blockDim.x + threadIdx.x;
  if (e >= E) return;
  int s = src[e], d = dst[e];
  unsigned pos = atomicAdd(&cursor[d], 1u);
  er[pos] = make_int2(s, __float_as_int(dinv[s]));
}

// one wave per dst node, lanes = features
template <int F>
__global__ __launch_bounds__(256) void k_gatherF(
    const unsigned* __restrict__ rowstart, const int2* __restrict__ er,
    const float* __restrict__ dinv, const float* __restrict__ feat,
    float* __restrict__ outp, int N) {
  int wid = (blockIdx.x * blockDim.x + threadIdx.x) >> 6;
  if (wid >= N) return;
  int lane = threadIdx.x & 63;
  unsigned s0 = rowstart[wid], s1 = rowstart[wid + 1];
  float dd = -dinv[wid];
  float acc0 = 0.0f, acc1 = 0.0f;
  for (unsigned e = s0; e < s1; ++e) {
    int2 r = er[e];
    float c = dd * __int_as_float(r.y);
    const float* row = feat + (size_t)r.x * F;
    if (F > 64) {
      acc0 += c * row[lane];
      if (lane < F - 64) acc1 += c * row[64 + lane];
    } else {
      if (lane < F) acc0 += c * row[lane];
    }
  }
  float* orow = outp + (size_t)wid * F;
  if (F > 64) {
    orow[lane] = acc0;
    if (lane < F - 64) orow[64 + lane] = acc1;
  } else {
    if (lane < F) orow[lane] = acc0;
  }
}

// F=1 propagate fused with final add: out[n] = a3[n] + sum_e w*g3[src]
__global__ void k_gather1(const unsigned* __restrict__ rowstart, const int2* __restrict__ er,
                          const float* __restrict__ dinv, const float* __restrict__ g3,
                          const float* __restrict__ a3, float* __restrict__ out, int N) {
  int n = blockIdx.x * blockDim.x + threadIdx.x;
  if (n >= N) return;
  unsigned s0 = rowstart[n], s1 = rowstart[n + 1];
  float dd = -dinv[n], acc = 0.0f;
  for (unsigned e = s0; e < s1; ++e) {
    int2 r = er[e];
    acc += dd * __int_as_float(r.y) * g3[r.x];
  }
  out[n] = a3[n] + acc;
}

// h1 = relu(x@W10 + p1@W11 + b1). x,p1:[N,58] W:[58,300]. 8 nodes/block, 320 thr.
#define MM1_TN 8
__global__ __launch_bounds__(320) void k_mm1(
    const float* __restrict__ x, const float* __restrict__ p1,
    const float* __restrict__ W10, const float* __restrict__ W11,
    const float* __restrict__ b1, float* __restrict__ h1, int N) {
  __shared__ __align__(16) float sx[MM1_TN * 60];
  __shared__ __align__(16) float sp[MM1_TN * 60];
  int n0 = blockIdx.x * MM1_TN;
  int t = threadIdx.x;
  int nrows = min(MM1_TN, N - n0);
  for (int idx = t; idx < nrows * 58; idx += 320) {
    int n = idx / 58, k = idx - n * 58;
    sx[n * 60 + k] = x[(size_t)n0 * 58 + idx];
    sp[n * 60 + k] = p1[(size_t)n0 * 58 + idx];
  }
  __syncthreads();
  int j = t;
  if (j >= 300) return;
  float acc[MM1_TN];
  float bb = b1[j];
#pragma unroll
  for (int n = 0; n < MM1_TN; n++) acc[n] = bb;
  for (int k = 0; k < 56; k += 4) {
    float wa0 = W10[(k + 0) * 300 + j], wa1 = W10[(k + 1) * 300 + j];
    float wa2 = W10[(k + 2) * 300 + j], wa3 = W10[(k + 3) * 300 + j];
    float wb0 = W11[(k + 0) * 300 + j], wb1 = W11[(k + 1) * 300 + j];
    float wb2 = W11[(k + 2) * 300 + j], wb3 = W11[(k + 3) * 300 + j];
#pragma unroll
    for (int n = 0; n < MM1_TN; n++) {
      float4 xv = *(const float4*)&sx[n * 60 + k];
      float4 pv = *(const float4*)&sp[n * 60 + k];
      acc[n] += xv.x * wa0 + xv.y * wa1 + xv.z * wa2 + xv.w * wa3;
      acc[n] += pv.x * wb0 + pv.y * wb1 + pv.z * wb2 + pv.w * wb3;
    }
  }
  for (int k = 56; k < 58; k++) {
    float wa = W10[k * 300 + j], wb = W11[k * 300 + j];
#pragma unroll
    for (int n = 0; n < MM1_TN; n++)
      acc[n] += sx[n * 60 + k] * wa + sp[n * 60 + k] * wb;
  }
  for (int n = 0; n < nrows; n++)
    h1[(size_t)(n0 + n) * 300 + j] = fmaxf(acc[n], 0.0f);
}

// out[n,j] = act( h[n,:]@W[:,j] (+ add + bias) ). h:[N,300] W:[300,100]. 16 nodes/block.
#define MM2_TN 16
template <bool ADDBIAS>
__global__ __launch_bounds__(128) void k_mm2(
    const float* __restrict__ h, const float* __restrict__ W,
    const float* __restrict__ bias, const float* __restrict__ add,
    float* __restrict__ out, int N) {
  __shared__ __align__(16) float sh[MM2_TN * 300];
  int n0 = blockIdx.x * MM2_TN;
  int t = threadIdx.x;
  int nrows = min(MM2_TN, N - n0);
  for (int idx = t; idx < nrows * 300; idx += 128)
    sh[idx] = h[(size_t)n0 * 300 + idx];
  __syncthreads();
  if (t >= 100) return;
  float acc[MM2_TN];
#pragma unroll
  for (int n = 0; n < MM2_TN; n++) acc[n] = 0.0f;
  for (int k = 0; k < 300; k += 4) {
    float w0 = W[(k + 0) * 100 + t], w1 = W[(k + 1) * 100 + t];
    float w2 = W[(k + 2) * 100 + t], w3 = W[(k + 3) * 100 + t];
#pragma unroll
    for (int n = 0; n < MM2_TN; n++) {
      float4 hv = *(const float4*)&sh[n * 300 + k];
      acc[n] += hv.x * w0 + hv.y * w1 + hv.z * w2 + hv.w * w3;
    }
  }
  for (int n = 0; n < nrows; n++) {
    float v = acc[n];
    if (ADDBIAS) {
      v += add[(size_t)(n0 + n) * 100 + t] + bias[t];
      v = fmaxf(v, 0.0f);
    }
    out[(size_t)(n0 + n) * 100 + t] = v;
  }
}

// per-node dual dot: a3 = h2@W30 + b3 ; g3 = h2@W31. one wave per node.
__global__ void k_mm3(const float* __restrict__ h2, const float* __restrict__ W30,
                      const float* __restrict__ W31, const float* __restrict__ b3,
                      float* __restrict__ a3, float* __restrict__ g3, int N) {
  int wid = (blockIdx.x * blockDim.x + threadIdx.x) >> 6;
  if (wid >= N) return;
  int lane = threadIdx.x & 63;
  const float* row = h2 + (size_t)wid * 100;
  float a = 0.0f, g = 0.0f;
  for (int f = lane; f < 100; f += 64) {
    float v = row[f];
    a += v * W30[f];
    g += v * W31[f];
  }
#pragma unroll
  for (int off = 32; off > 0; off >>= 1) {
    a += __shfl_down(a, off);
    g += __shfl_down(g, off);
  }
  if (lane == 0) {
    a3[wid] = a + b3[0];
    g3[wid] = g;
  }
}

extern "C" void kernel_launch(void* const* d_in, const int* in_sizes, int n_in,
                              void* d_out, int out_size, void* d_ws, size_t ws_size,
                              hipStream_t stream) {
  const float* x  = (const float*)d_in[0];
  const int*   ei = (const int*)d_in[1];
  const float* W1 = (const float*)d_in[2];  // [2][58][300]
  const float* b1 = (const float*)d_in[3];
  const float* W2 = (const float*)d_in[4];  // [2][300][100]
  const float* b2 = (const float*)d_in[5];
  const float* W3 = (const float*)d_in[6];  // [2][100][1]
  const float* b3 = (const float*)d_in[7];
  float* out = (float*)d_out;

  const int N = in_sizes[0] / 58;   // 100000
  const int E = in_sizes[1] / 2;    // 800000
  const int NB = (N + 1023) / 1024; // scan blocks (must be <= 256)
  const int* src = ei;
  const int* dst = ei + E;

  char* ws = (char*)d_ws;
  size_t off = 0;
  auto alloc = [&](size_t bytes) -> void* {
    void* p = ws + off;
    off += (bytes + 255) & ~(size_t)255;
    return p;
  };
  unsigned* deg      = (unsigned*)alloc((size_t)2 * N * 4);  // deg | cnt (one memset)
  unsigned* cnt      = deg + N;
  float*    dinv     = (float*)alloc((size_t)N * 4);
  unsigned* rowstart = (unsigned*)alloc((size_t)(N + 1) * 4);
  unsigned* cursor   = (unsigned*)alloc((size_t)N * 4);
  unsigned* btot     = (unsigned*)alloc((size_t)256 * 4);
  int2*     er       = (int2*)alloc((size_t)E * 8);
  float*    h1       = (float*)alloc((size_t)N * 300 * 4);
  float*    RA       = (float*)alloc((size_t)N * 100 * 4);  // p1 -> g2 -> h2
  float*    RB       = (float*)alloc((size_t)N * 100 * 4);  // p2 -> (g3,a3)
  float* p1 = RA;
  float* g2 = RA;
  float* h2 = RA;
  float* p2 = RB;
  float* g3 = RB;
  float* a3 = RB + N;

  const float* W10 = W1;
  const float* W11 = W1 + 58 * 300;
  const float* W20 = W2;
  const float* W21 = W2 + 300 * 100;
  const float* W30 = W3;
  const float* W31 = W3 + 100;

  // --- degrees + CSR (by dst) ---
  hipMemsetAsync(deg, 0, (size_t)2 * N * 4, stream);
  k_count<<<(E + 255) / 256, 256, 0, stream>>>(src, dst, deg, cnt, E);
  k_dinv<<<(N + 255) / 256, 256, 0, stream>>>(deg, dinv, N);
  k_scan1<<<NB, 256, 0, stream>>>(cnt, btot, N);
  k_scan2<<<1, 256, 0, stream>>>(btot, rowstart, NB, N, E);
  k_scan3<<<NB, 256, 0, stream>>>(cnt, btot, rowstart, cursor, N);
  k_fill<<<(E + 255) / 256, 256, 0, stream>>>(src, dst, dinv, cursor, er, E);

  // --- layer 1 ---
  k_gatherF<58><<<(N + 3) / 4, 256, 0, stream>>>(rowstart, er, dinv, x, p1, N);
  k_mm1<<<(N + MM1_TN - 1) / MM1_TN, 320, 0, stream>>>(x, p1, W10, W11, b1, h1, N);

  // --- layer 2 ---
  k_mm2<false><<<(N + MM2_TN - 1) / MM2_TN, 128, 0, stream>>>(h1, W21, nullptr, nullptr, g2, N);
  k_gatherF<100><<<(N + 3) / 4, 256, 0, stream>>>(rowstart, er, dinv, g2, p2, N);
  k_mm2<true><<<(N + MM2_TN - 1) / MM2_TN, 128, 0, stream>>>(h1, W20, b2, p2, h2, N);

  // --- layer 3 ---
  k_mm3<<<(N + 3) / 4, 256, 0, stream>>>(h2, W30, W31, b3, a3, g3, N);
  k_gather1<<<(N + 255) / 256, 256, 0, stream>>>(rowstart, er, dinv, g3, a3, out, N);
}

// Round 3
// 469.361 us; speedup vs baseline: 2.5269x; 1.8508x over previous
//
#include <hip/hip_runtime.h>

// ---------------------------------------------------------------------------
// EMOGI ChebConv-K2 x3 : N=100000 nodes, E=800000 edges, dims 58->300->100->1
// bf16 MFMA edition.
//   CSR by dst (count/scan/fill) -> gathers, no float atomics.
//   xb  [NR][128] bf16 = [x | p1 | 0]       (p1 filled by gather58)
//   h1b [NR][320] bf16 = relu([x|p1]@[W10;W11] + b1), K-pad cols zeroed
//   mm2: g2 = h1@W21, a2 = h1@W20 (one pass over h1b), both bf16 [N][104]
//   gather_l2: p2 = prop(g2); h2 = relu(a2+p2+b2) in-reg; a3,g3 = h2@W3 dots
//   gather1: out = a3 + prop(g3)
// MFMA: 16x16x32 bf16, A-frags in registers (32 rows/wave), B from global
// (L2-hot pre-transposed weights). D layout: col=lane&15, row=(lane>>4)*4+i.
// ---------------------------------------------------------------------------

typedef short bf16x8 __attribute__((ext_vector_type(8)));
typedef float f32x4 __attribute__((ext_vector_type(4)));

__device__ __forceinline__ unsigned f2bf(float f) {  // RNE fp32->bf16 bits
  unsigned u = __float_as_uint(f);
  u += 0x7fff + ((u >> 16) & 1);
  return u >> 16;
}
__device__ __forceinline__ float bf2f(unsigned s) {
  return __uint_as_float(s << 16);
}

// ---------------- CSR build ----------------
__global__ void k_count(const int* __restrict__ src, const int* __restrict__ dst,
                        unsigned* __restrict__ deg, unsigned* __restrict__ cnt, int E) {
  int i = blockIdx.x * blockDim.x + threadIdx.x;
  if (i < E) {
    atomicAdd(&deg[src[i]], 1u);
    atomicAdd(&cnt[dst[i]], 1u);
  }
}

__global__ void k_dinv(const unsigned* __restrict__ deg, float* __restrict__ dinv, int N) {
  int i = blockIdx.x * blockDim.x + threadIdx.x;
  if (i < N) {
    unsigned d = deg[i];
    dinv[i] = d ? rsqrtf((float)d) : 0.0f;
  }
}

__global__ __launch_bounds__(256) void k_scan1(const unsigned* __restrict__ cnt,
                                               unsigned* __restrict__ btot, int N) {
  __shared__ unsigned s[256];
  int b = blockIdx.x, t = threadIdx.x;
  int base = b * 1024;
  unsigned sum = 0;
  for (int i = t; i < 1024; i += 256) {
    int idx = base + i;
    sum += (idx < N) ? cnt[idx] : 0u;
  }
  s[t] = sum;
  __syncthreads();
  for (int off = 128; off > 0; off >>= 1) {
    if (t < off) s[t] += s[t + off];
    __syncthreads();
  }
  if (t == 0) btot[b] = s[0];
}

__global__ __launch_bounds__(256) void k_scan2(unsigned* __restrict__ btot,
                                               unsigned* __restrict__ rowstart,
                                               int NB, int N, int E) {
  __shared__ unsigned s[256];
  int t = threadIdx.x;
  s[t] = (t < NB) ? btot[t] : 0u;
  __syncthreads();
  if (t == 0) {
    unsigned acc = 0;
    for (int i = 0; i < NB; i++) { unsigned v = s[i]; s[i] = acc; acc += v; }
  }
  __syncthreads();
  if (t < NB) btot[t] = s[t];
  if (t == 0) rowstart[N] = (unsigned)E;
}

__global__ __launch_bounds__(256) void k_scan3(const unsigned* __restrict__ cnt,
                                               const unsigned* __restrict__ btot,
                                               unsigned* __restrict__ rowstart,
                                               unsigned* __restrict__ cursor, int N) {
  __shared__ unsigned ssum[256];
  int b = blockIdx.x, t = threadIdx.x;
  int base = b * 1024 + t * 4;
  unsigned v0 = 0, v1 = 0, v2 = 0, v3 = 0;
  if (base + 0 < N) v0 = cnt[base + 0];
  if (base + 1 < N) v1 = cnt[base + 1];
  if (base + 2 < N) v2 = cnt[base + 2];
  if (base + 3 < N) v3 = cnt[base + 3];
  ssum[t] = v0 + v1 + v2 + v3;
  __syncthreads();
  for (int off = 1; off < 256; off <<= 1) {
    unsigned add = (t >= off) ? ssum[t - off] : 0u;
    __syncthreads();
    ssum[t] += add;
    __syncthreads();
  }
  unsigned texcl = ((t == 0) ? 0u : ssum[t - 1]) + btot[b];
  unsigned r0 = texcl, r1 = r0 + v0, r2 = r1 + v1, r3 = r2 + v2;
  if (base + 0 < N) { rowstart[base + 0] = r0; cursor[base + 0] = r0; }
  if (base + 1 < N) { rowstart[base + 1] = r1; cursor[base + 1] = r1; }
  if (base + 2 < N) { rowstart[base + 2] = r2; cursor[base + 2] = r2; }
  if (base + 3 < N) { rowstart[base + 3] = r3; cursor[base + 3] = r3; }
}

__global__ void k_fill(const int* __restrict__ src, const int* __restrict__ dst,
                       const float* __restrict__ dinv, unsigned* __restrict__ cursor,
                       int2* __restrict__ er, int E) {
  int e = blockIdx.x * blockDim.x + threadIdx.x;
  if (e >= E) return;
  int s = src[e], d = dst[e];
  unsigned pos = atomicAdd(&cursor[d], 1u);
  er[pos] = make_int2(s, __float_as_int(dinv[s]));
}

// ---------------- prep kernels ----------------
// xb[n][0..57] = bf16(x[n]); xb[n][116..127] = 0. (58..115 by gather58)
__global__ void k_prep_xb(const float* __restrict__ x, unsigned short* __restrict__ xb, int N) {
  int idx = blockIdx.x * blockDim.x + threadIdx.x;
  int n = idx >> 6, p = idx & 63;
  if (n >= N) return;
  int c = p * 2;
  if (c < 58) {
    unsigned lo = f2bf(x[(size_t)n * 58 + c]);
    unsigned hi = f2bf(x[(size_t)n * 58 + c + 1]);
    *(unsigned*)(xb + (size_t)n * 128 + c) = lo | (hi << 16);
  } else if (c >= 116) {
    *(unsigned*)(xb + (size_t)n * 128 + c) = 0;
  }
}

// Wt1[j][k], j<304 (cols of layer1 out), k<128: [W10;W11] transposed, bf16
__global__ void k_prep_w1(const float* __restrict__ W1, unsigned short* __restrict__ Wt1) {
  int idx = blockIdx.x * blockDim.x + threadIdx.x;
  int j = idx >> 6, p = idx & 63;
  if (j >= 304) return;
  int k = p * 2;
  unsigned v[2];
#pragma unroll
  for (int q = 0; q < 2; q++) {
    int kk = k + q;
    float f = 0.0f;
    if (j < 300) {
      if (kk < 58) f = W1[kk * 300 + j];
      else if (kk < 116) f = W1[17400 + (kk - 58) * 300 + j];
    }
    v[q] = f2bf(f);
  }
  *(unsigned*)(Wt1 + j * 128 + k) = v[0] | (v[1] << 16);
}

// Wt2[r][k], r<208, k<320: rows 0..99 = W21^T (g2), 104..203 = W20^T (a2)
__global__ void k_prep_w2(const float* __restrict__ W2, unsigned short* __restrict__ Wt2) {
  int idx = blockIdx.x * blockDim.x + threadIdx.x;
  int r = idx / 160, p = idx % 160;
  if (r >= 208) return;
  int k = p * 2;
  unsigned v[2];
#pragma unroll
  for (int q = 0; q < 2; q++) {
    int kk = k + q;
    float f = 0.0f;
    if (kk < 300) {
      if (r < 100) f = W2[30000 + kk * 100 + r];
      else if (r >= 104 && r < 204) f = W2[kk * 100 + (r - 104)];
    }
    v[q] = f2bf(f);
  }
  *(unsigned*)(Wt2 + r * 320 + k) = v[0] | (v[1] << 16);
}

// zero h1b K-pad cols 300..319 for all NR rows
__global__ void k_zero_h1pad(unsigned short* __restrict__ h1b, int NR) {
  int idx = blockIdx.x * blockDim.x + threadIdx.x;
  int r = idx / 10, p = idx % 10;
  if (r >= NR) return;
  *(unsigned*)(h1b + (size_t)r * 320 + 300 + p * 2) = 0;
}

// ---------------- gathers ----------------
// p1 = prop(x) in bf16: reads xb[:,0..57], writes xb[:,58..115]. wave/node.
__global__ __launch_bounds__(256) void k_gather58(
    const unsigned* __restrict__ rowstart, const int2* __restrict__ er,
    const float* __restrict__ dinv, unsigned short* __restrict__ xb, int N) {
  int wid = (blockIdx.x * blockDim.x + threadIdx.x) >> 6;
  if (wid >= N) return;
  int lane = threadIdx.x & 63;
  int c0 = lane * 2;
  if (c0 >= 58) return;
  unsigned s0 = rowstart[wid], s1 = rowstart[wid + 1];
  float dd = -dinv[wid];
  float p0 = 0.f, p1 = 0.f;
  for (unsigned e = s0; e < s1; ++e) {
    int2 r = er[e];
    float cw = dd * __int_as_float(r.y);
    unsigned v = *(const unsigned*)(xb + (size_t)r.x * 128 + c0);
    p0 += cw * bf2f(v & 0xffffu);
    p1 += cw * bf2f(v >> 16);
  }
  *(unsigned*)(xb + (size_t)wid * 128 + 58 + c0) = f2bf(p0) | (f2bf(p1) << 16);
}

// layer2 tail fused: p2 = prop(g2); h2 = relu(a2+p2+b2); a3,g3 = h2@W30/W31
__global__ __launch_bounds__(256) void k_gather_l2(
    const unsigned* __restrict__ rowstart, const int2* __restrict__ er,
    const float* __restrict__ dinv,
    const unsigned short* __restrict__ g2b, const unsigned short* __restrict__ a2b,
    const float* __restrict__ b2, const float* __restrict__ W30,
    const float* __restrict__ W31, const float* __restrict__ b3,
    float* __restrict__ a3, float* __restrict__ g3, int N) {
  int wid = (blockIdx.x * blockDim.x + threadIdx.x) >> 6;
  if (wid >= N) return;
  int lane = threadIdx.x & 63;
  int c0 = lane * 2;
  bool act = c0 < 100;
  unsigned s0 = rowstart[wid], s1 = rowstart[wid + 1];
  float dd = -dinv[wid];
  float p0 = 0.f, p1 = 0.f;
  if (act) {
    for (unsigned e = s0; e < s1; ++e) {
      int2 r = er[e];
      float cw = dd * __int_as_float(r.y);
      unsigned v = *(const unsigned*)(g2b + (size_t)r.x * 104 + c0);
      p0 += cw * bf2f(v & 0xffffu);
      p1 += cw * bf2f(v >> 16);
    }
  }
  float aa = 0.f, gg = 0.f;
  if (act) {
    unsigned av = *(const unsigned*)(a2b + (size_t)wid * 104 + c0);
    float h0 = fmaxf(bf2f(av & 0xffffu) + p0 + b2[c0], 0.f);
    float h1 = fmaxf(bf2f(av >> 16) + p1 + b2[c0 + 1], 0.f);
    aa = h0 * W30[c0] + h1 * W30[c0 + 1];
    gg = h0 * W31[c0] + h1 * W31[c0 + 1];
  }
#pragma unroll
  for (int off = 32; off > 0; off >>= 1) {
    aa += __shfl_xor(aa, off);
    gg += __shfl_xor(gg, off);
  }
  if (lane == 0) {
    a3[wid] = aa + b3[0];
    g3[wid] = gg;
  }
}

// out = a3 + prop(g3), thread/node
__global__ void k_gather1(const unsigned* __restrict__ rowstart, const int2* __restrict__ er,
                          const float* __restrict__ dinv, const float* __restrict__ g3,
                          const float* __restrict__ a3, float* __restrict__ out, int N) {
  int n = blockIdx.x * blockDim.x + threadIdx.x;
  if (n >= N) return;
  unsigned s0 = rowstart[n], s1 = rowstart[n + 1];
  float dd = -dinv[n], acc = 0.0f;
  for (unsigned e = s0; e < s1; ++e) {
    int2 r = er[e];
    acc += dd * __int_as_float(r.y) * g3[r.x];
  }
  out[n] = a3[n] + acc;
}

// ---------------- MFMA matmuls ----------------
// h1b = relu(xb @ Wt1^T + b1). 128 rows/block (4 waves x 32), K=128, 19 col-tiles.
__global__ __launch_bounds__(256) void k_mm1_mfma(
    const unsigned short* __restrict__ xb, const unsigned short* __restrict__ Wt1,
    const float* __restrict__ b1, unsigned short* __restrict__ h1b, int N) {
  int wv = threadIdx.x >> 6, lane = threadIdx.x & 63;
  int rbase = blockIdx.x * 128 + wv * 32;
  int lr = lane & 15, lk = (lane >> 4) * 8;
  bf16x8 a[2][4];
#pragma unroll
  for (int rt = 0; rt < 2; rt++)
#pragma unroll
    for (int s = 0; s < 4; s++)
      a[rt][s] = *(const bf16x8*)(xb + (size_t)(rbase + rt * 16 + lr) * 128 + s * 32 + lk);
  for (int j = 0; j < 19; j++) {
    int c = j * 16 + lr;
    f32x4 acc0 = {0.f, 0.f, 0.f, 0.f}, acc1 = {0.f, 0.f, 0.f, 0.f};
#pragma unroll
    for (int s = 0; s < 4; s++) {
      bf16x8 b = *(const bf16x8*)(Wt1 + (size_t)c * 128 + s * 32 + lk);
      acc0 = __builtin_amdgcn_mfma_f32_16x16x32_bf16(a[0][s], b, acc0, 0, 0, 0);
      acc1 = __builtin_amdgcn_mfma_f32_16x16x32_bf16(a[1][s], b, acc1, 0, 0, 0);
    }
    if (c < 300) {
      float bias = b1[c];
      int r0 = rbase + (lane >> 4) * 4;
#pragma unroll
      for (int i = 0; i < 4; i++) {
        int r = r0 + i;
        if (r < N) h1b[(size_t)r * 320 + c] = (unsigned short)f2bf(fmaxf(acc0[i] + bias, 0.f));
        if (r + 16 < N) h1b[(size_t)(r + 16) * 320 + c] = (unsigned short)f2bf(fmaxf(acc1[i] + bias, 0.f));
      }
    }
  }
}

// g2b | a2b = h1b @ Wt2^T. K=320 (10 steps), 13 col-tiles (0..103 g2, 104..207 a2)
__global__ __launch_bounds__(256) void k_mm2_mfma(
    const unsigned short* __restrict__ h1b, const unsigned short* __restrict__ Wt2,
    unsigned short* __restrict__ g2b, unsigned short* __restrict__ a2b, int N) {
  int wv = threadIdx.x >> 6, lane = threadIdx.x & 63;
  int rbase = blockIdx.x * 128 + wv * 32;
  int lr = lane & 15, lk = (lane >> 4) * 8;
  bf16x8 a[2][10];
#pragma unroll
  for (int rt = 0; rt < 2; rt++)
#pragma unroll
    for (int s = 0; s < 10; s++)
      a[rt][s] = *(const bf16x8*)(h1b + (size_t)(rbase + rt * 16 + lr) * 320 + s * 32 + lk);
  for (int j = 0; j < 13; j++) {
    int c = j * 16 + lr;
    f32x4 acc0 = {0.f, 0.f, 0.f, 0.f}, acc1 = {0.f, 0.f, 0.f, 0.f};
#pragma unroll
    for (int s = 0; s < 10; s++) {
      bf16x8 b = *(const bf16x8*)(Wt2 + (size_t)c * 320 + s * 32 + lk);
      acc0 = __builtin_amdgcn_mfma_f32_16x16x32_bf16(a[0][s], b, acc0, 0, 0, 0);
      acc1 = __builtin_amdgcn_mfma_f32_16x16x32_bf16(a[1][s], b, acc1, 0, 0, 0);
    }
    int r0 = rbase + (lane >> 4) * 4;
    unsigned short* outp = (c < 104) ? g2b : a2b;
    int cc = (c < 104) ? c : c - 104;
#pragma unroll
    for (int i = 0; i < 4; i++) {
      int r = r0 + i;
      if (r < N) outp[(size_t)r * 104 + cc] = (unsigned short)f2bf(acc0[i]);
      if (r + 16 < N) outp[(size_t)(r + 16) * 104 + cc] = (unsigned short)f2bf(acc1[i]);
    }
  }
}

// ---------------- launch ----------------
extern "C" void kernel_launch(void* const* d_in, const int* in_sizes, int n_in,
                              void* d_out, int out_size, void* d_ws, size_t ws_size,
                              hipStream_t stream) {
  const float* x  = (const float*)d_in[0];
  const int*   ei = (const int*)d_in[1];
  const float* W1 = (const float*)d_in[2];  // [2][58][300]
  const float* b1 = (const float*)d_in[3];
  const float* W2 = (const float*)d_in[4];  // [2][300][100]
  const float* b2 = (const float*)d_in[5];
  const float* W3 = (const float*)d_in[6];  // [2][100][1]
  const float* b3 = (const float*)d_in[7];
  float* out = (float*)d_out;

  const int N = in_sizes[0] / 58;            // 100000
  const int E = in_sizes[1] / 2;             // 800000
  const int NR = (N + 127) & ~127;           // 100096
  const int NB = (N + 1023) / 1024;
  const int* src = ei;
  const int* dst = ei + E;

  char* ws = (char*)d_ws;
  size_t off = 0;
  auto alloc = [&](size_t bytes) -> void* {
    void* p = ws + off;
    off += (bytes + 255) & ~(size_t)255;
    return p;
  };
  unsigned* deg      = (unsigned*)alloc((size_t)2 * N * 4);
  unsigned* cnt      = deg + N;
  float*    dinv     = (float*)alloc((size_t)N * 4);
  unsigned* rowstart = (unsigned*)alloc((size_t)(N + 1) * 4);
  unsigned* cursor   = (unsigned*)alloc((size_t)N * 4);
  unsigned* btot     = (unsigned*)alloc((size_t)256 * 4);
  int2*     er       = (int2*)alloc((size_t)E * 8);
  unsigned short* xb  = (unsigned short*)alloc((size_t)NR * 128 * 2);
  unsigned short* Wt1 = (unsigned short*)alloc((size_t)304 * 128 * 2);
  unsigned short* Wt2 = (unsigned short*)alloc((size_t)208 * 320 * 2);
  unsigned short* h1b = (unsigned short*)alloc((size_t)NR * 320 * 2);
  unsigned short* g2b = (unsigned short*)alloc((size_t)N * 104 * 2);
  unsigned short* a2b = (unsigned short*)alloc((size_t)N * 104 * 2);
  float* a3 = (float*)alloc((size_t)N * 4);
  float* g3 = (float*)alloc((size_t)N * 4);

  // --- CSR + dinv ---
  hipMemsetAsync(deg, 0, (size_t)2 * N * 4, stream);
  k_count<<<(E + 255) / 256, 256, 0, stream>>>(src, dst, deg, cnt, E);
  k_dinv<<<(N + 255) / 256, 256, 0, stream>>>(deg, dinv, N);
  k_scan1<<<NB, 256, 0, stream>>>(cnt, btot, N);
  k_scan2<<<1, 256, 0, stream>>>(btot, rowstart, NB, N, E);
  k_scan3<<<NB, 256, 0, stream>>>(cnt, btot, rowstart, cursor, N);
  k_fill<<<(E + 255) / 256, 256, 0, stream>>>(src, dst, dinv, cursor, er, E);

  // --- preps ---
  k_prep_w1<<<(304 * 64 + 255) / 256, 256, 0, stream>>>(W1, Wt1);
  k_prep_w2<<<(208 * 160 + 255) / 256, 256, 0, stream>>>(W2, Wt2);
  k_prep_xb<<<((size_t)N * 64 + 255) / 256, 256, 0, stream>>>(x, xb, N);
  k_zero_h1pad<<<((size_t)NR * 10 + 255) / 256, 256, 0, stream>>>(h1b, NR);

  // --- layer 1 ---
  k_gather58<<<(N + 3) / 4, 256, 0, stream>>>(rowstart, er, dinv, xb, N);
  k_mm1_mfma<<<NR / 128, 256, 0, stream>>>(xb, Wt1, b1, h1b, N);

  // --- layer 2 ---
  k_mm2_mfma<<<NR / 128, 256, 0, stream>>>(h1b, Wt2, g2b, a2b, N);
  k_gather_l2<<<(N + 3) / 4, 256, 0, stream>>>(rowstart, er, dinv, g2b, a2b,
                                               b2, W3, W3 + 100, b3, a3, g3, N);

  // --- layer 3 ---
  k_gather1<<<(N + 255) / 256, 256, 0, stream>>>(rowstart, er, dinv, g3, a3, out, N);
}

// Round 4
// 402.048 us; speedup vs baseline: 2.9499x; 1.1674x over previous
//
#include <hip/hip_runtime.h>

// ---------------------------------------------------------------------------
// EMOGI ChebConv-K2 x3 : N=100000 nodes, E=800000 edges, dims 58->300->100->1
// bf16 MFMA edition + MLP-unrolled gathers.
//   CSR by dst (count/scan/fill) -> gathers, no float atomics.
//   xb  [NR][128] bf16 = [x | p1 | 0]       (p1 filled by gather58)
//   h1b [NR][320] bf16 = relu([x|p1]@[W10;W11] + b1), K-pad cols zeroed
//   mm2: g2 = h1@W21, a2 = h1@W20 (one pass over h1b), both bf16 [N][104]
//   gather_l2: p2 = prop(g2); h2 = relu(a2+p2+b2) in-reg; a3,g3 = h2@W3 dots
//   gather1: out = a3 + prop(g3)
// Gathers are latency-bound pointer chases -> edge loop unrolled x4 with
// independent accumulators (4 row loads in flight per wave).
// ---------------------------------------------------------------------------

typedef short bf16x8 __attribute__((ext_vector_type(8)));
typedef float f32x4 __attribute__((ext_vector_type(4)));

__device__ __forceinline__ unsigned f2bf(float f) {  // RNE fp32->bf16 bits
  unsigned u = __float_as_uint(f);
  u += 0x7fff + ((u >> 16) & 1);
  return u >> 16;
}
__device__ __forceinline__ float bf2f(unsigned s) {
  return __uint_as_float(s << 16);
}

// ---------------- CSR build ----------------
__global__ void k_count(const int* __restrict__ src, const int* __restrict__ dst,
                        unsigned* __restrict__ deg, unsigned* __restrict__ cnt, int E) {
  int i = blockIdx.x * blockDim.x + threadIdx.x;
  if (i < E) {
    atomicAdd(&deg[src[i]], 1u);
    atomicAdd(&cnt[dst[i]], 1u);
  }
}

__global__ void k_dinv(const unsigned* __restrict__ deg, float* __restrict__ dinv, int N) {
  int i = blockIdx.x * blockDim.x + threadIdx.x;
  if (i < N) {
    unsigned d = deg[i];
    dinv[i] = d ? rsqrtf((float)d) : 0.0f;
  }
}

__global__ __launch_bounds__(256) void k_scan1(const unsigned* __restrict__ cnt,
                                               unsigned* __restrict__ btot, int N) {
  __shared__ unsigned s[256];
  int b = blockIdx.x, t = threadIdx.x;
  int base = b * 1024;
  unsigned sum = 0;
  for (int i = t; i < 1024; i += 256) {
    int idx = base + i;
    sum += (idx < N) ? cnt[idx] : 0u;
  }
  s[t] = sum;
  __syncthreads();
  for (int off = 128; off > 0; off >>= 1) {
    if (t < off) s[t] += s[t + off];
    __syncthreads();
  }
  if (t == 0) btot[b] = s[0];
}

__global__ __launch_bounds__(256) void k_scan2(unsigned* __restrict__ btot,
                                               unsigned* __restrict__ rowstart,
                                               int NB, int N, int E) {
  __shared__ unsigned s[256];
  int t = threadIdx.x;
  s[t] = (t < NB) ? btot[t] : 0u;
  __syncthreads();
  if (t == 0) {
    unsigned acc = 0;
    for (int i = 0; i < NB; i++) { unsigned v = s[i]; s[i] = acc; acc += v; }
  }
  __syncthreads();
  if (t < NB) btot[t] = s[t];
  if (t == 0) rowstart[N] = (unsigned)E;
}

__global__ __launch_bounds__(256) void k_scan3(const unsigned* __restrict__ cnt,
                                               const unsigned* __restrict__ btot,
                                               unsigned* __restrict__ rowstart,
                                               unsigned* __restrict__ cursor, int N) {
  __shared__ unsigned ssum[256];
  int b = blockIdx.x, t = threadIdx.x;
  int base = b * 1024 + t * 4;
  unsigned v0 = 0, v1 = 0, v2 = 0, v3 = 0;
  if (base + 0 < N) v0 = cnt[base + 0];
  if (base + 1 < N) v1 = cnt[base + 1];
  if (base + 2 < N) v2 = cnt[base + 2];
  if (base + 3 < N) v3 = cnt[base + 3];
  ssum[t] = v0 + v1 + v2 + v3;
  __syncthreads();
  for (int off = 1; off < 256; off <<= 1) {
    unsigned add = (t >= off) ? ssum[t - off] : 0u;
    __syncthreads();
    ssum[t] += add;
    __syncthreads();
  }
  unsigned texcl = ((t == 0) ? 0u : ssum[t - 1]) + btot[b];
  unsigned r0 = texcl, r1 = r0 + v0, r2 = r1 + v1, r3 = r2 + v2;
  if (base + 0 < N) { rowstart[base + 0] = r0; cursor[base + 0] = r0; }
  if (base + 1 < N) { rowstart[base + 1] = r1; cursor[base + 1] = r1; }
  if (base + 2 < N) { rowstart[base + 2] = r2; cursor[base + 2] = r2; }
  if (base + 3 < N) { rowstart[base + 3] = r3; cursor[base + 3] = r3; }
}

__global__ void k_fill(const int* __restrict__ src, const int* __restrict__ dst,
                       const float* __restrict__ dinv, unsigned* __restrict__ cursor,
                       int2* __restrict__ er, int E) {
  int e = blockIdx.x * blockDim.x + threadIdx.x;
  if (e >= E) return;
  int s = src[e], d = dst[e];
  unsigned pos = atomicAdd(&cursor[d], 1u);
  er[pos] = make_int2(s, __float_as_int(dinv[s]));
}

// ---------------- prep kernels ----------------
__global__ void k_prep_xb(const float* __restrict__ x, unsigned short* __restrict__ xb, int N) {
  int idx = blockIdx.x * blockDim.x + threadIdx.x;
  int n = idx >> 6, p = idx & 63;
  if (n >= N) return;
  int c = p * 2;
  if (c < 58) {
    unsigned lo = f2bf(x[(size_t)n * 58 + c]);
    unsigned hi = f2bf(x[(size_t)n * 58 + c + 1]);
    *(unsigned*)(xb + (size_t)n * 128 + c) = lo | (hi << 16);
  } else if (c >= 116) {
    *(unsigned*)(xb + (size_t)n * 128 + c) = 0;
  }
}

__global__ void k_prep_w1(const float* __restrict__ W1, unsigned short* __restrict__ Wt1) {
  int idx = blockIdx.x * blockDim.x + threadIdx.x;
  int j = idx >> 6, p = idx & 63;
  if (j >= 304) return;
  int k = p * 2;
  unsigned v[2];
#pragma unroll
  for (int q = 0; q < 2; q++) {
    int kk = k + q;
    float f = 0.0f;
    if (j < 300) {
      if (kk < 58) f = W1[kk * 300 + j];
      else if (kk < 116) f = W1[17400 + (kk - 58) * 300 + j];
    }
    v[q] = f2bf(f);
  }
  *(unsigned*)(Wt1 + j * 128 + k) = v[0] | (v[1] << 16);
}

__global__ void k_prep_w2(const float* __restrict__ W2, unsigned short* __restrict__ Wt2) {
  int idx = blockIdx.x * blockDim.x + threadIdx.x;
  int r = idx / 160, p = idx % 160;
  if (r >= 208) return;
  int k = p * 2;
  unsigned v[2];
#pragma unroll
  for (int q = 0; q < 2; q++) {
    int kk = k + q;
    float f = 0.0f;
    if (kk < 300) {
      if (r < 100) f = W2[30000 + kk * 100 + r];
      else if (r >= 104 && r < 204) f = W2[kk * 100 + (r - 104)];
    }
    v[q] = f2bf(f);
  }
  *(unsigned*)(Wt2 + r * 320 + k) = v[0] | (v[1] << 16);
}

__global__ void k_zero_h1pad(unsigned short* __restrict__ h1b, int NR) {
  int idx = blockIdx.x * blockDim.x + threadIdx.x;
  int r = idx / 10, p = idx % 10;
  if (r >= NR) return;
  *(unsigned*)(h1b + (size_t)r * 320 + 300 + p * 2) = 0;
}

// ---------------- gathers (x4 MLP-unrolled) ----------------
// p1 = prop(x): reads xb[:,0..57], writes xb[:,58..115]. wave/node.
__global__ __launch_bounds__(256) void k_gather58(
    const unsigned* __restrict__ rowstart, const int2* __restrict__ er,
    const float* __restrict__ dinv, unsigned short* __restrict__ xb, int N) {
  int wid = (blockIdx.x * blockDim.x + threadIdx.x) >> 6;
  if (wid >= N) return;
  int lane = threadIdx.x & 63;
  int c0 = lane * 2;
  if (c0 >= 58) return;
  unsigned s0 = rowstart[wid], s1 = rowstart[wid + 1];
  float a0 = 0.f, a1 = 0.f, b0 = 0.f, b1 = 0.f;
  float c0a = 0.f, c1a = 0.f, d0 = 0.f, d1 = 0.f;
  unsigned e = s0;
  for (; e + 4 <= s1; e += 4) {
    int2 r0 = er[e], r1 = er[e + 1], r2 = er[e + 2], r3 = er[e + 3];
    unsigned v0 = *(const unsigned*)(xb + (size_t)r0.x * 128 + c0);
    unsigned v1 = *(const unsigned*)(xb + (size_t)r1.x * 128 + c0);
    unsigned v2 = *(const unsigned*)(xb + (size_t)r2.x * 128 + c0);
    unsigned v3 = *(const unsigned*)(xb + (size_t)r3.x * 128 + c0);
    float w0 = __int_as_float(r0.y), w1 = __int_as_float(r1.y);
    float w2 = __int_as_float(r2.y), w3 = __int_as_float(r3.y);
    a0 += w0 * bf2f(v0 & 0xffffu); a1 += w0 * bf2f(v0 >> 16);
    b0 += w1 * bf2f(v1 & 0xffffu); b1 += w1 * bf2f(v1 >> 16);
    c0a += w2 * bf2f(v2 & 0xffffu); c1a += w2 * bf2f(v2 >> 16);
    d0 += w3 * bf2f(v3 & 0xffffu); d1 += w3 * bf2f(v3 >> 16);
  }
  for (; e < s1; ++e) {
    int2 r = er[e];
    float w = __int_as_float(r.y);
    unsigned v = *(const unsigned*)(xb + (size_t)r.x * 128 + c0);
    a0 += w * bf2f(v & 0xffffu); a1 += w * bf2f(v >> 16);
  }
  float dd = -dinv[wid];
  float p0 = dd * ((a0 + b0) + (c0a + d0));
  float p1 = dd * ((a1 + b1) + (c1a + d1));
  *(unsigned*)(xb + (size_t)wid * 128 + 58 + c0) = f2bf(p0) | (f2bf(p1) << 16);
}

// layer2 tail fused: p2 = prop(g2); h2 = relu(a2+p2+b2); a3,g3 = h2@W30/W31
__global__ __launch_bounds__(256) void k_gather_l2(
    const unsigned* __restrict__ rowstart, const int2* __restrict__ er,
    const float* __restrict__ dinv,
    const unsigned short* __restrict__ g2b, const unsigned short* __restrict__ a2b,
    const float* __restrict__ b2, const float* __restrict__ W30,
    const float* __restrict__ W31, const float* __restrict__ b3,
    float* __restrict__ a3, float* __restrict__ g3, int N) {
  int wid = (blockIdx.x * blockDim.x + threadIdx.x) >> 6;
  if (wid >= N) return;
  int lane = threadIdx.x & 63;
  int c0 = lane * 2;
  bool act = c0 < 100;
  unsigned s0 = rowstart[wid], s1 = rowstart[wid + 1];
  float aa = 0.f, gg = 0.f;
  if (act) {
    float a0 = 0.f, a1 = 0.f, b0 = 0.f, b1 = 0.f;
    float c0a = 0.f, c1a = 0.f, d0 = 0.f, d1 = 0.f;
    unsigned e = s0;
    for (; e + 4 <= s1; e += 4) {
      int2 r0 = er[e], r1 = er[e + 1], r2 = er[e + 2], r3 = er[e + 3];
      unsigned v0 = *(const unsigned*)(g2b + (size_t)r0.x * 104 + c0);
      unsigned v1 = *(const unsigned*)(g2b + (size_t)r1.x * 104 + c0);
      unsigned v2 = *(const unsigned*)(g2b + (size_t)r2.x * 104 + c0);
      unsigned v3 = *(const unsigned*)(g2b + (size_t)r3.x * 104 + c0);
      float w0 = __int_as_float(r0.y), w1 = __int_as_float(r1.y);
      float w2 = __int_as_float(r2.y), w3 = __int_as_float(r3.y);
      a0 += w0 * bf2f(v0 & 0xffffu); a1 += w0 * bf2f(v0 >> 16);
      b0 += w1 * bf2f(v1 & 0xffffu); b1 += w1 * bf2f(v1 >> 16);
      c0a += w2 * bf2f(v2 & 0xffffu); c1a += w2 * bf2f(v2 >> 16);
      d0 += w3 * bf2f(v3 & 0xffffu); d1 += w3 * bf2f(v3 >> 16);
    }
    for (; e < s1; ++e) {
      int2 r = er[e];
      float w = __int_as_float(r.y);
      unsigned v = *(const unsigned*)(g2b + (size_t)r.x * 104 + c0);
      a0 += w * bf2f(v & 0xffffu); a1 += w * bf2f(v >> 16);
    }
    float dd = -dinv[wid];
    float p0 = dd * ((a0 + b0) + (c0a + d0));
    float p1 = dd * ((a1 + b1) + (c1a + d1));
    unsigned av = *(const unsigned*)(a2b + (size_t)wid * 104 + c0);
    float h0 = fmaxf(bf2f(av & 0xffffu) + p0 + b2[c0], 0.f);
    float h1 = fmaxf(bf2f(av >> 16) + p1 + b2[c0 + 1], 0.f);
    aa = h0 * W30[c0] + h1 * W30[c0 + 1];
    gg = h0 * W31[c0] + h1 * W31[c0 + 1];
  }
#pragma unroll
  for (int off = 32; off > 0; off >>= 1) {
    aa += __shfl_xor(aa, off);
    gg += __shfl_xor(gg, off);
  }
  if (lane == 0) {
    a3[wid] = aa + b3[0];
    g3[wid] = gg;
  }
}

// out = a3 + prop(g3), thread/node, x4 unrolled
__global__ void k_gather1(const unsigned* __restrict__ rowstart, const int2* __restrict__ er,
                          const float* __restrict__ dinv, const float* __restrict__ g3,
                          const float* __restrict__ a3, float* __restrict__ out, int N) {
  int n = blockIdx.x * blockDim.x + threadIdx.x;
  if (n >= N) return;
  unsigned s0 = rowstart[n], s1 = rowstart[n + 1];
  float a = 0.f, b = 0.f, c = 0.f, d = 0.f;
  unsigned e = s0;
  for (; e + 4 <= s1; e += 4) {
    int2 r0 = er[e], r1 = er[e + 1], r2 = er[e + 2], r3 = er[e + 3];
    float g0 = g3[r0.x], g1 = g3[r1.x], g2v = g3[r2.x], g3v = g3[r3.x];
    a += __int_as_float(r0.y) * g0;
    b += __int_as_float(r1.y) * g1;
    c += __int_as_float(r2.y) * g2v;
    d += __int_as_float(r3.y) * g3v;
  }
  for (; e < s1; ++e) {
    int2 r = er[e];
    a += __int_as_float(r.y) * g3[r.x];
  }
  out[n] = a3[n] - dinv[n] * ((a + b) + (c + d));
}

// ---------------- MFMA matmuls ----------------
__global__ __launch_bounds__(256) void k_mm1_mfma(
    const unsigned short* __restrict__ xb, const unsigned short* __restrict__ Wt1,
    const float* __restrict__ b1, unsigned short* __restrict__ h1b, int N) {
  int wv = threadIdx.x >> 6, lane = threadIdx.x & 63;
  int rbase = blockIdx.x * 128 + wv * 32;
  int lr = lane & 15, lk = (lane >> 4) * 8;
  bf16x8 a[2][4];
#pragma unroll
  for (int rt = 0; rt < 2; rt++)
#pragma unroll
    for (int s = 0; s < 4; s++)
      a[rt][s] = *(const bf16x8*)(xb + (size_t)(rbase + rt * 16 + lr) * 128 + s * 32 + lk);
  for (int j = 0; j < 19; j++) {
    int c = j * 16 + lr;
    f32x4 acc0 = {0.f, 0.f, 0.f, 0.f}, acc1 = {0.f, 0.f, 0.f, 0.f};
#pragma unroll
    for (int s = 0; s < 4; s++) {
      bf16x8 b = *(const bf16x8*)(Wt1 + (size_t)c * 128 + s * 32 + lk);
      acc0 = __builtin_amdgcn_mfma_f32_16x16x32_bf16(a[0][s], b, acc0, 0, 0, 0);
      acc1 = __builtin_amdgcn_mfma_f32_16x16x32_bf16(a[1][s], b, acc1, 0, 0, 0);
    }
    if (c < 300) {
      float bias = b1[c];
      int r0 = rbase + (lane >> 4) * 4;
#pragma unroll
      for (int i = 0; i < 4; i++) {
        int r = r0 + i;
        if (r < N) h1b[(size_t)r * 320 + c] = (unsigned short)f2bf(fmaxf(acc0[i] + bias, 0.f));
        if (r + 16 < N) h1b[(size_t)(r + 16) * 320 + c] = (unsigned short)f2bf(fmaxf(acc1[i] + bias, 0.f));
      }
    }
  }
}

__global__ __launch_bounds__(256) void k_mm2_mfma(
    const unsigned short* __restrict__ h1b, const unsigned short* __restrict__ Wt2,
    unsigned short* __restrict__ g2b, unsigned short* __restrict__ a2b, int N) {
  int wv = threadIdx.x >> 6, lane = threadIdx.x & 63;
  int rbase = blockIdx.x * 128 + wv * 32;
  int lr = lane & 15, lk = (lane >> 4) * 8;
  bf16x8 a[2][10];
#pragma unroll
  for (int rt = 0; rt < 2; rt++)
#pragma unroll
    for (int s = 0; s < 10; s++)
      a[rt][s] = *(const bf16x8*)(h1b + (size_t)(rbase + rt * 16 + lr) * 320 + s * 32 + lk);
  for (int j = 0; j < 13; j++) {
    int c = j * 16 + lr;
    f32x4 acc0 = {0.f, 0.f, 0.f, 0.f}, acc1 = {0.f, 0.f, 0.f, 0.f};
#pragma unroll
    for (int s = 0; s < 10; s++) {
      bf16x8 b = *(const bf16x8*)(Wt2 + (size_t)c * 320 + s * 32 + lk);
      acc0 = __builtin_amdgcn_mfma_f32_16x16x32_bf16(a[0][s], b, acc0, 0, 0, 0);
      acc1 = __builtin_amdgcn_mfma_f32_16x16x32_bf16(a[1][s], b, acc1, 0, 0, 0);
    }
    int r0 = rbase + (lane >> 4) * 4;
    unsigned short* outp = (c < 104) ? g2b : a2b;
    int cc = (c < 104) ? c : c - 104;
#pragma unroll
    for (int i = 0; i < 4; i++) {
      int r = r0 + i;
      if (r < N) outp[(size_t)r * 104 + cc] = (unsigned short)f2bf(acc0[i]);
      if (r + 16 < N) outp[(size_t)(r + 16) * 104 + cc] = (unsigned short)f2bf(acc1[i]);
    }
  }
}

// ---------------- launch ----------------
extern "C" void kernel_launch(void* const* d_in, const int* in_sizes, int n_in,
                              void* d_out, int out_size, void* d_ws, size_t ws_size,
                              hipStream_t stream) {
  const float* x  = (const float*)d_in[0];
  const int*   ei = (const int*)d_in[1];
  const float* W1 = (const float*)d_in[2];  // [2][58][300]
  const float* b1 = (const float*)d_in[3];
  const float* W2 = (const float*)d_in[4];  // [2][300][100]
  const float* b2 = (const float*)d_in[5];
  const float* W3 = (const float*)d_in[6];  // [2][100][1]
  const float* b3 = (const float*)d_in[7];
  float* out = (float*)d_out;

  const int N = in_sizes[0] / 58;            // 100000
  const int E = in_sizes[1] / 2;             // 800000
  const int NR = (N + 127) & ~127;           // 100096
  const int NB = (N + 1023) / 1024;
  const int* src = ei;
  const int* dst = ei + E;

  char* ws = (char*)d_ws;
  size_t off = 0;
  auto alloc = [&](size_t bytes) -> void* {
    void* p = ws + off;
    off += (bytes + 255) & ~(size_t)255;
    return p;
  };
  unsigned* deg      = (unsigned*)alloc((size_t)2 * N * 4);
  unsigned* cnt      = deg + N;
  float*    dinv     = (float*)alloc((size_t)N * 4);
  unsigned* rowstart = (unsigned*)alloc((size_t)(N + 1) * 4);
  unsigned* cursor   = (unsigned*)alloc((size_t)N * 4);
  unsigned* btot     = (unsigned*)alloc((size_t)256 * 4);
  int2*     er       = (int2*)alloc((size_t)E * 8);
  unsigned short* xb  = (unsigned short*)alloc((size_t)NR * 128 * 2);
  unsigned short* Wt1 = (unsigned short*)alloc((size_t)304 * 128 * 2);
  unsigned short* Wt2 = (unsigned short*)alloc((size_t)208 * 320 * 2);
  unsigned short* h1b = (unsigned short*)alloc((size_t)NR * 320 * 2);
  unsigned short* g2b = (unsigned short*)alloc((size_t)N * 104 * 2);
  unsigned short* a2b = (unsigned short*)alloc((size_t)N * 104 * 2);
  float* a3 = (float*)alloc((size_t)N * 4);
  float* g3 = (float*)alloc((size_t)N * 4);

  // --- CSR + dinv ---
  hipMemsetAsync(deg, 0, (size_t)2 * N * 4, stream);
  k_count<<<(E + 255) / 256, 256, 0, stream>>>(src, dst, deg, cnt, E);
  k_dinv<<<(N + 255) / 256, 256, 0, stream>>>(deg, dinv, N);
  k_scan1<<<NB, 256, 0, stream>>>(cnt, btot, N);
  k_scan2<<<1, 256, 0, stream>>>(btot, rowstart, NB, N, E);
  k_scan3<<<NB, 256, 0, stream>>>(cnt, btot, rowstart, cursor, N);
  k_fill<<<(E + 255) / 256, 256, 0, stream>>>(src, dst, dinv, cursor, er, E);

  // --- preps ---
  k_prep_w1<<<(304 * 64 + 255) / 256, 256, 0, stream>>>(W1, Wt1);
  k_prep_w2<<<(208 * 160 + 255) / 256, 256, 0, stream>>>(W2, Wt2);
  k_prep_xb<<<((size_t)N * 64 + 255) / 256, 256, 0, stream>>>(x, xb, N);
  k_zero_h1pad<<<((size_t)NR * 10 + 255) / 256, 256, 0, stream>>>(h1b, NR);

  // --- layer 1 ---
  k_gather58<<<(N + 3) / 4, 256, 0, stream>>>(rowstart, er, dinv, xb, N);
  k_mm1_mfma<<<NR / 128, 256, 0, stream>>>(xb, Wt1, b1, h1b, N);

  // --- layer 2 ---
  k_mm2_mfma<<<NR / 128, 256, 0, stream>>>(h1b, Wt2, g2b, a2b, N);
  k_gather_l2<<<(N + 3) / 4, 256, 0, stream>>>(rowstart, er, dinv, g2b, a2b,
                                               b2, W3, W3 + 100, b3, a3, g3, N);

  // --- layer 3 ---
  k_gather1<<<(N + 255) / 256, 256, 0, stream>>>(rowstart, er, dinv, g3, a3, out, N);
}

// Round 5
// 390.454 us; speedup vs baseline: 3.0375x; 1.0297x over previous
//
#include <hip/hip_runtime.h>

// ---------------------------------------------------------------------------
// EMOGI ChebConv-K2 x3 : N=100000 nodes, E=800000 edges, dims 58->300->100->1
// bf16 MFMA edition + MLP-unrolled gathers + LDS-staged coalesced C-writes.
//   CSR by dst (count/scan/fill) -> gathers, no float atomics.
//   xb  [NR][128] bf16 = [x | p1 | 0]       (p1 filled by gather58)
//   h1b [NR][320] bf16 = relu([x|p1]@[W10;W11] + b1), K-pad cols zeroed
//   mm2: ga2b[NR][208] = h1b @ [W21|pad|W20|pad]^T (cols 0..99 g2, 104..203 a2)
//   gather_l2: p2 = prop(g2); h2 = relu(a2+p2+b2) in-reg; a3,g3 = h2@W3 dots
//   gather1: out = a3 + prop(g3)
// MFMA outputs are staged per-wave in LDS then copied as contiguous uint4
// spans (wave rows are consecutive nodes) -> no partial-cacheline RMW.
// ---------------------------------------------------------------------------

typedef short bf16x8 __attribute__((ext_vector_type(8)));
typedef float f32x4 __attribute__((ext_vector_type(4)));

__device__ __forceinline__ unsigned f2bf(float f) {  // RNE fp32->bf16 bits
  unsigned u = __float_as_uint(f);
  u += 0x7fff + ((u >> 16) & 1);
  return u >> 16;
}
__device__ __forceinline__ float bf2f(unsigned s) {
  return __uint_as_float(s << 16);
}

// ---------------- CSR build ----------------
__global__ void k_count(const int* __restrict__ src, const int* __restrict__ dst,
                        unsigned* __restrict__ deg, unsigned* __restrict__ cnt, int E) {
  int i = blockIdx.x * blockDim.x + threadIdx.x;
  if (i < E) {
    atomicAdd(&deg[src[i]], 1u);
    atomicAdd(&cnt[dst[i]], 1u);
  }
}

__global__ void k_dinv(const unsigned* __restrict__ deg, float* __restrict__ dinv, int N) {
  int i = blockIdx.x * blockDim.x + threadIdx.x;
  if (i < N) {
    unsigned d = deg[i];
    dinv[i] = d ? rsqrtf((float)d) : 0.0f;
  }
}

__global__ __launch_bounds__(256) void k_scan1(const unsigned* __restrict__ cnt,
                                               unsigned* __restrict__ btot, int N) {
  __shared__ unsigned s[256];
  int b = blockIdx.x, t = threadIdx.x;
  int base = b * 1024;
  unsigned sum = 0;
  for (int i = t; i < 1024; i += 256) {
    int idx = base + i;
    sum += (idx < N) ? cnt[idx] : 0u;
  }
  s[t] = sum;
  __syncthreads();
  for (int off = 128; off > 0; off >>= 1) {
    if (t < off) s[t] += s[t + off];
    __syncthreads();
  }
  if (t == 0) btot[b] = s[0];
}

__global__ __launch_bounds__(256) void k_scan2(unsigned* __restrict__ btot,
                                               unsigned* __restrict__ rowstart,
                                               int NB, int N, int E) {
  __shared__ unsigned s[256];
  int t = threadIdx.x;
  s[t] = (t < NB) ? btot[t] : 0u;
  __syncthreads();
  if (t == 0) {
    unsigned acc = 0;
    for (int i = 0; i < NB; i++) { unsigned v = s[i]; s[i] = acc; acc += v; }
  }
  __syncthreads();
  if (t < NB) btot[t] = s[t];
  if (t == 0) rowstart[N] = (unsigned)E;
}

__global__ __launch_bounds__(256) void k_scan3(const unsigned* __restrict__ cnt,
                                               const unsigned* __restrict__ btot,
                                               unsigned* __restrict__ rowstart,
                                               unsigned* __restrict__ cursor, int N) {
  __shared__ unsigned ssum[256];
  int b = blockIdx.x, t = threadIdx.x;
  int base = b * 1024 + t * 4;
  unsigned v0 = 0, v1 = 0, v2 = 0, v3 = 0;
  if (base + 0 < N) v0 = cnt[base + 0];
  if (base + 1 < N) v1 = cnt[base + 1];
  if (base + 2 < N) v2 = cnt[base + 2];
  if (base + 3 < N) v3 = cnt[base + 3];
  ssum[t] = v0 + v1 + v2 + v3;
  __syncthreads();
  for (int off = 1; off < 256; off <<= 1) {
    unsigned add = (t >= off) ? ssum[t - off] : 0u;
    __syncthreads();
    ssum[t] += add;
    __syncthreads();
  }
  unsigned texcl = ((t == 0) ? 0u : ssum[t - 1]) + btot[b];
  unsigned r0 = texcl, r1 = r0 + v0, r2 = r1 + v1, r3 = r2 + v2;
  if (base + 0 < N) { rowstart[base + 0] = r0; cursor[base + 0] = r0; }
  if (base + 1 < N) { rowstart[base + 1] = r1; cursor[base + 1] = r1; }
  if (base + 2 < N) { rowstart[base + 2] = r2; cursor[base + 2] = r2; }
  if (base + 3 < N) { rowstart[base + 3] = r3; cursor[base + 3] = r3; }
}

__global__ void k_fill(const int* __restrict__ src, const int* __restrict__ dst,
                       const float* __restrict__ dinv, unsigned* __restrict__ cursor,
                       int2* __restrict__ er, int E) {
  int e = blockIdx.x * blockDim.x + threadIdx.x;
  if (e >= E) return;
  int s = src[e], d = dst[e];
  unsigned pos = atomicAdd(&cursor[d], 1u);
  er[pos] = make_int2(s, __float_as_int(dinv[s]));
}

// ---------------- prep kernels ----------------
__global__ void k_prep_xb(const float* __restrict__ x, unsigned short* __restrict__ xb, int N) {
  int idx = blockIdx.x * blockDim.x + threadIdx.x;
  int n = idx >> 6, p = idx & 63;
  if (n >= N) return;
  int c = p * 2;
  if (c < 58) {
    unsigned lo = f2bf(x[(size_t)n * 58 + c]);
    unsigned hi = f2bf(x[(size_t)n * 58 + c + 1]);
    *(unsigned*)(xb + (size_t)n * 128 + c) = lo | (hi << 16);
  } else if (c >= 116) {
    *(unsigned*)(xb + (size_t)n * 128 + c) = 0;
  }
}

__global__ void k_prep_w1(const float* __restrict__ W1, unsigned short* __restrict__ Wt1) {
  int idx = blockIdx.x * blockDim.x + threadIdx.x;
  int j = idx >> 6, p = idx & 63;
  if (j >= 304) return;
  int k = p * 2;
  unsigned v[2];
#pragma unroll
  for (int q = 0; q < 2; q++) {
    int kk = k + q;
    float f = 0.0f;
    if (j < 300) {
      if (kk < 58) f = W1[kk * 300 + j];
      else if (kk < 116) f = W1[17400 + (kk - 58) * 300 + j];
    }
    v[q] = f2bf(f);
  }
  *(unsigned*)(Wt1 + j * 128 + k) = v[0] | (v[1] << 16);
}

__global__ void k_prep_w2(const float* __restrict__ W2, unsigned short* __restrict__ Wt2) {
  int idx = blockIdx.x * blockDim.x + threadIdx.x;
  int r = idx / 160, p = idx % 160;
  if (r >= 208) return;
  int k = p * 2;
  unsigned v[2];
#pragma unroll
  for (int q = 0; q < 2; q++) {
    int kk = k + q;
    float f = 0.0f;
    if (kk < 300) {
      if (r < 100) f = W2[30000 + kk * 100 + r];
      else if (r >= 104 && r < 204) f = W2[kk * 100 + (r - 104)];
    }
    v[q] = f2bf(f);
  }
  *(unsigned*)(Wt2 + r * 320 + k) = v[0] | (v[1] << 16);
}

// ---------------- gathers (x4 MLP-unrolled) ----------------
__global__ __launch_bounds__(256) void k_gather58(
    const unsigned* __restrict__ rowstart, const int2* __restrict__ er,
    const float* __restrict__ dinv, unsigned short* __restrict__ xb, int N) {
  int wid = (blockIdx.x * blockDim.x + threadIdx.x) >> 6;
  if (wid >= N) return;
  int lane = threadIdx.x & 63;
  int c0 = lane * 2;
  if (c0 >= 58) return;
  unsigned s0 = rowstart[wid], s1 = rowstart[wid + 1];
  float a0 = 0.f, a1 = 0.f, b0 = 0.f, b1 = 0.f;
  float c0a = 0.f, c1a = 0.f, d0 = 0.f, d1 = 0.f;
  unsigned e = s0;
  for (; e + 4 <= s1; e += 4) {
    int2 r0 = er[e], r1 = er[e + 1], r2 = er[e + 2], r3 = er[e + 3];
    unsigned v0 = *(const unsigned*)(xb + (size_t)r0.x * 128 + c0);
    unsigned v1 = *(const unsigned*)(xb + (size_t)r1.x * 128 + c0);
    unsigned v2 = *(const unsigned*)(xb + (size_t)r2.x * 128 + c0);
    unsigned v3 = *(const unsigned*)(xb + (size_t)r3.x * 128 + c0);
    float w0 = __int_as_float(r0.y), w1 = __int_as_float(r1.y);
    float w2 = __int_as_float(r2.y), w3 = __int_as_float(r3.y);
    a0 += w0 * bf2f(v0 & 0xffffu); a1 += w0 * bf2f(v0 >> 16);
    b0 += w1 * bf2f(v1 & 0xffffu); b1 += w1 * bf2f(v1 >> 16);
    c0a += w2 * bf2f(v2 & 0xffffu); c1a += w2 * bf2f(v2 >> 16);
    d0 += w3 * bf2f(v3 & 0xffffu); d1 += w3 * bf2f(v3 >> 16);
  }
  for (; e < s1; ++e) {
    int2 r = er[e];
    float w = __int_as_float(r.y);
    unsigned v = *(const unsigned*)(xb + (size_t)r.x * 128 + c0);
    a0 += w * bf2f(v & 0xffffu); a1 += w * bf2f(v >> 16);
  }
  float dd = -dinv[wid];
  float p0 = dd * ((a0 + b0) + (c0a + d0));
  float p1 = dd * ((a1 + b1) + (c1a + d1));
  *(unsigned*)(xb + (size_t)wid * 128 + 58 + c0) = f2bf(p0) | (f2bf(p1) << 16);
}

// layer2 tail fused: p2 = prop(g2); h2 = relu(a2+p2+b2); a3,g3 = h2@W30/W31
// ga2b row: cols 0..99 = g2, 104..203 = a2 (stride 208)
__global__ __launch_bounds__(256) void k_gather_l2(
    const unsigned* __restrict__ rowstart, const int2* __restrict__ er,
    const float* __restrict__ dinv, const unsigned short* __restrict__ ga2b,
    const float* __restrict__ b2, const float* __restrict__ W30,
    const float* __restrict__ W31, const float* __restrict__ b3,
    float* __restrict__ a3, float* __restrict__ g3, int N) {
  int wid = (blockIdx.x * blockDim.x + threadIdx.x) >> 6;
  if (wid >= N) return;
  int lane = threadIdx.x & 63;
  int c0 = lane * 2;
  bool act = c0 < 100;
  unsigned s0 = rowstart[wid], s1 = rowstart[wid + 1];
  float aa = 0.f, gg = 0.f;
  if (act) {
    float a0 = 0.f, a1 = 0.f, b0 = 0.f, b1 = 0.f;
    float c0a = 0.f, c1a = 0.f, d0 = 0.f, d1 = 0.f;
    unsigned e = s0;
    for (; e + 4 <= s1; e += 4) {
      int2 r0 = er[e], r1 = er[e + 1], r2 = er[e + 2], r3 = er[e + 3];
      unsigned v0 = *(const unsigned*)(ga2b + (size_t)r0.x * 208 + c0);
      unsigned v1 = *(const unsigned*)(ga2b + (size_t)r1.x * 208 + c0);
      unsigned v2 = *(const unsigned*)(ga2b + (size_t)r2.x * 208 + c0);
      unsigned v3 = *(const unsigned*)(ga2b + (size_t)r3.x * 208 + c0);
      float w0 = __int_as_float(r0.y), w1 = __int_as_float(r1.y);
      float w2 = __int_as_float(r2.y), w3 = __int_as_float(r3.y);
      a0 += w0 * bf2f(v0 & 0xffffu); a1 += w0 * bf2f(v0 >> 16);
      b0 += w1 * bf2f(v1 & 0xffffu); b1 += w1 * bf2f(v1 >> 16);
      c0a += w2 * bf2f(v2 & 0xffffu); c1a += w2 * bf2f(v2 >> 16);
      d0 += w3 * bf2f(v3 & 0xffffu); d1 += w3 * bf2f(v3 >> 16);
    }
    for (; e < s1; ++e) {
      int2 r = er[e];
      float w = __int_as_float(r.y);
      unsigned v = *(const unsigned*)(ga2b + (size_t)r.x * 208 + c0);
      a0 += w * bf2f(v & 0xffffu); a1 += w * bf2f(v >> 16);
    }
    float dd = -dinv[wid];
    float p0 = dd * ((a0 + b0) + (c0a + d0));
    float p1 = dd * ((a1 + b1) + (c1a + d1));
    unsigned av = *(const unsigned*)(ga2b + (size_t)wid * 208 + 104 + c0);
    float h0 = fmaxf(bf2f(av & 0xffffu) + p0 + b2[c0], 0.f);
    float h1 = fmaxf(bf2f(av >> 16) + p1 + b2[c0 + 1], 0.f);
    aa = h0 * W30[c0] + h1 * W30[c0 + 1];
    gg = h0 * W31[c0] + h1 * W31[c0 + 1];
  }
#pragma unroll
  for (int off = 32; off > 0; off >>= 1) {
    aa += __shfl_xor(aa, off);
    gg += __shfl_xor(gg, off);
  }
  if (lane == 0) {
    a3[wid] = aa + b3[0];
    g3[wid] = gg;
  }
}

__global__ void k_gather1(const unsigned* __restrict__ rowstart, const int2* __restrict__ er,
                          const float* __restrict__ dinv, const float* __restrict__ g3,
                          const float* __restrict__ a3, float* __restrict__ out, int N) {
  int n = blockIdx.x * blockDim.x + threadIdx.x;
  if (n >= N) return;
  unsigned s0 = rowstart[n], s1 = rowstart[n + 1];
  float a = 0.f, b = 0.f, c = 0.f, d = 0.f;
  unsigned e = s0;
  for (; e + 4 <= s1; e += 4) {
    int2 r0 = er[e], r1 = er[e + 1], r2 = er[e + 2], r3 = er[e + 3];
    float g0 = g3[r0.x], g1 = g3[r1.x], g2v = g3[r2.x], g3v = g3[r3.x];
    a += __int_as_float(r0.y) * g0;
    b += __int_as_float(r1.y) * g1;
    c += __int_as_float(r2.y) * g2v;
    d += __int_as_float(r3.y) * g3v;
  }
  for (; e < s1; ++e) {
    int2 r = er[e];
    a += __int_as_float(r.y) * g3[r.x];
  }
  out[n] = a3[n] - dinv[n] * ((a + b) + (c + d));
}

// ---------------- MFMA matmuls (LDS-staged coalesced C-writes) ----------------
// h1b = relu(xb @ Wt1^T + b1). 4 waves x 32 rows, K=128. Columns in two
// 160-wide halves staged per-wave in LDS, copied as uint4 (320 B runs/row).
__global__ __launch_bounds__(256) void k_mm1_mfma(
    const unsigned short* __restrict__ xb, const unsigned short* __restrict__ Wt1,
    const float* __restrict__ b1, unsigned short* __restrict__ h1b) {
  __shared__ unsigned short tile[4][32][160];  // 40 KB
  int wv = threadIdx.x >> 6, lane = threadIdx.x & 63;
  int rbase = blockIdx.x * 128 + wv * 32;
  int lr = lane & 15, lk = (lane >> 4) * 8;
  bf16x8 a[2][4];
#pragma unroll
  for (int rt = 0; rt < 2; rt++)
#pragma unroll
    for (int s = 0; s < 4; s++)
      a[rt][s] = *(const bf16x8*)(xb + (size_t)(rbase + rt * 16 + lr) * 128 + s * 32 + lk);
#pragma unroll
  for (int half = 0; half < 2; half++) {
    int j0 = half * 10, j1 = half ? 19 : 10;
    for (int j = j0; j < j1; j++) {
      int c = j * 16 + lr;
      f32x4 acc0 = {0.f, 0.f, 0.f, 0.f}, acc1 = {0.f, 0.f, 0.f, 0.f};
#pragma unroll
      for (int s = 0; s < 4; s++) {
        bf16x8 b = *(const bf16x8*)(Wt1 + (size_t)c * 128 + s * 32 + lk);
        acc0 = __builtin_amdgcn_mfma_f32_16x16x32_bf16(a[0][s], b, acc0, 0, 0, 0);
        acc1 = __builtin_amdgcn_mfma_f32_16x16x32_bf16(a[1][s], b, acc1, 0, 0, 0);
      }
      float bias = (c < 300) ? b1[c] : 0.0f;
      int lc = c - half * 160;
      int r0 = (lane >> 4) * 4;
#pragma unroll
      for (int i = 0; i < 4; i++) {
        unsigned short v0 = (c < 300) ? (unsigned short)f2bf(fmaxf(acc0[i] + bias, 0.f)) : 0;
        unsigned short v1 = (c < 300) ? (unsigned short)f2bf(fmaxf(acc1[i] + bias, 0.f)) : 0;
        tile[wv][r0 + i][lc] = v0;
        tile[wv][r0 + 16 + i][lc] = v1;
      }
    }
    if (half == 1) {  // zero K-pad cols 304..319 (local 144..159)
      for (int idx = lane; idx < 32 * 16; idx += 64)
        tile[wv][idx >> 4][144 + (idx & 15)] = 0;
    }
    // copy wave tile: 32 rows x 320 B at global row stride 640 B
    for (int idx = lane; idx < 32 * 20; idx += 64) {
      int row = idx / 20, q = idx % 20;
      *(uint4*)(h1b + (size_t)(rbase + row) * 320 + half * 160 + q * 8) =
          *(const uint4*)&tile[wv][row][q * 8];
    }
  }
}

// ga2b = h1b @ Wt2^T. K=320 (10 steps), 13 col-tiles. Wave tile 32x208 staged
// in LDS, copied as one 13312 B contiguous span (rows consecutive).
__global__ __launch_bounds__(256) void k_mm2_mfma(
    const unsigned short* __restrict__ h1b, const unsigned short* __restrict__ Wt2,
    unsigned short* __restrict__ ga2b) {
  __shared__ unsigned short tile[4][32][208];  // 52 KB
  int wv = threadIdx.x >> 6, lane = threadIdx.x & 63;
  int rbase = blockIdx.x * 128 + wv * 32;
  int lr = lane & 15, lk = (lane >> 4) * 8;
  bf16x8 a[2][10];
#pragma unroll
  for (int rt = 0; rt < 2; rt++)
#pragma unroll
    for (int s = 0; s < 10; s++)
      a[rt][s] = *(const bf16x8*)(h1b + (size_t)(rbase + rt * 16 + lr) * 320 + s * 32 + lk);
  for (int j = 0; j < 13; j++) {
    int c = j * 16 + lr;
    f32x4 acc0 = {0.f, 0.f, 0.f, 0.f}, acc1 = {0.f, 0.f, 0.f, 0.f};
#pragma unroll
    for (int s = 0; s < 10; s++) {
      bf16x8 b = *(const bf16x8*)(Wt2 + (size_t)c * 320 + s * 32 + lk);
      acc0 = __builtin_amdgcn_mfma_f32_16x16x32_bf16(a[0][s], b, acc0, 0, 0, 0);
      acc1 = __builtin_amdgcn_mfma_f32_16x16x32_bf16(a[1][s], b, acc1, 0, 0, 0);
    }
    int r0 = (lane >> 4) * 4;
#pragma unroll
    for (int i = 0; i < 4; i++) {
      tile[wv][r0 + i][c] = (unsigned short)f2bf(acc0[i]);
      tile[wv][r0 + 16 + i][c] = (unsigned short)f2bf(acc1[i]);
    }
  }
  // wave tile = rows rbase..rbase+31, 208 cols -> 13312 contiguous bytes
  const uint4* lsrc = (const uint4*)&tile[wv][0][0];
  uint4* gdst = (uint4*)(ga2b + (size_t)rbase * 208);
  for (int idx = lane; idx < 832; idx += 64) gdst[idx] = lsrc[idx];
}

// ---------------- launch ----------------
extern "C" void kernel_launch(void* const* d_in, const int* in_sizes, int n_in,
                              void* d_out, int out_size, void* d_ws, size_t ws_size,
                              hipStream_t stream) {
  const float* x  = (const float*)d_in[0];
  const int*   ei = (const int*)d_in[1];
  const float* W1 = (const float*)d_in[2];  // [2][58][300]
  const float* b1 = (const float*)d_in[3];
  const float* W2 = (const float*)d_in[4];  // [2][300][100]
  const float* b2 = (const float*)d_in[5];
  const float* W3 = (const float*)d_in[6];  // [2][100][1]
  const float* b3 = (const float*)d_in[7];
  float* out = (float*)d_out;

  const int N = in_sizes[0] / 58;            // 100000
  const int E = in_sizes[1] / 2;             // 800000
  const int NR = (N + 127) & ~127;           // 100096
  const int NB = (N + 1023) / 1024;
  const int* src = ei;
  const int* dst = ei + E;

  char* ws = (char*)d_ws;
  size_t off = 0;
  auto alloc = [&](size_t bytes) -> void* {
    void* p = ws + off;
    off += (bytes + 255) & ~(size_t)255;
    return p;
  };
  unsigned* deg      = (unsigned*)alloc((size_t)2 * N * 4);
  unsigned* cnt      = deg + N;
  float*    dinv     = (float*)alloc((size_t)N * 4);
  unsigned* rowstart = (unsigned*)alloc((size_t)(N + 1) * 4);
  unsigned* cursor   = (unsigned*)alloc((size_t)N * 4);
  unsigned* btot     = (unsigned*)alloc((size_t)256 * 4);
  int2*     er       = (int2*)alloc((size_t)E * 8);
  unsigned short* xb   = (unsigned short*)alloc((size_t)NR * 128 * 2);
  unsigned short* Wt1  = (unsigned short*)alloc((size_t)304 * 128 * 2);
  unsigned short* Wt2  = (unsigned short*)alloc((size_t)208 * 320 * 2);
  unsigned short* h1b  = (unsigned short*)alloc((size_t)NR * 320 * 2);
  unsigned short* ga2b = (unsigned short*)alloc((size_t)NR * 208 * 2);
  float* a3 = (float*)alloc((size_t)N * 4);
  float* g3 = (float*)alloc((size_t)N * 4);

  // --- CSR + dinv ---
  hipMemsetAsync(deg, 0, (size_t)2 * N * 4, stream);
  k_count<<<(E + 255) / 256, 256, 0, stream>>>(src, dst, deg, cnt, E);
  k_dinv<<<(N + 255) / 256, 256, 0, stream>>>(deg, dinv, N);
  k_scan1<<<NB, 256, 0, stream>>>(cnt, btot, N);
  k_scan2<<<1, 256, 0, stream>>>(btot, rowstart, NB, N, E);
  k_scan3<<<NB, 256, 0, stream>>>(cnt, btot, rowstart, cursor, N);
  k_fill<<<(E + 255) / 256, 256, 0, stream>>>(src, dst, dinv, cursor, er, E);

  // --- preps ---
  k_prep_w1<<<(304 * 64 + 255) / 256, 256, 0, stream>>>(W1, Wt1);
  k_prep_w2<<<(208 * 160 + 255) / 256, 256, 0, stream>>>(W2, Wt2);
  k_prep_xb<<<((size_t)N * 64 + 255) / 256, 256, 0, stream>>>(x, xb, N);

  // --- layer 1 ---
  k_gather58<<<(N + 3) / 4, 256, 0, stream>>>(rowstart, er, dinv, xb, N);
  k_mm1_mfma<<<NR / 128, 256, 0, stream>>>(xb, Wt1, b1, h1b);

  // --- layer 2 ---
  k_mm2_mfma<<<NR / 128, 256, 0, stream>>>(h1b, Wt2, ga2b);
  k_gather_l2<<<(N + 3) / 4, 256, 0, stream>>>(rowstart, er, dinv, ga2b,
                                               b2, W3, W3 + 100, b3, a3, g3, N);

  // --- layer 3 ---
  k_gather1<<<(N + 255) / 256, 256, 0, stream>>>(rowstart, er, dinv, g3, a3, out, N);
}

// Round 6
// 383.762 us; speedup vs baseline: 3.0905x; 1.0174x over previous
//
#include <hip/hip_runtime.h>

// ---------------------------------------------------------------------------
// EMOGI ChebConv-K2 x3 : N=100000 nodes, E=800000 edges, dims 58->300->100->1
// bf16 MFMA edition + MLP-unrolled gathers + LDS-staged coalesced C-writes.
//   CSR by dst (count/scan/fill) -> gathers, no float atomics.
//   xb  [NR][128] bf16 = [x | p1 | 0]       (p1 filled by gather58)
//   h1b [NR][320] bf16 = relu([x|p1]@[W10;W11] + b1), K-pad cols zeroed
//   mm2: ga2b[NR][208] = h1b @ [W21|pad|W20|pad]^T (cols 0..99 g2, 104..203 a2)
//   gather_l2: p2 = prop(g2); h2 = relu(a2+p2+b2) in-reg; a3,g3 = h2@W3 dots
//   gather1: out = a3 + prop(g3)
// R5 lesson: mm2 at launch_bounds(256) got VGPR=68 < the 80 needed for its
// A-fragments alone -> spill/remat of strided global loads inside the j-loop
// (81us, MfmaUtil 6%). LDS already caps occupancy (mm2: 3 blk/CU, mm1: 4),
// so raise the VGPR cap to exactly that occupancy: (256,3) / (256,4).
// ---------------------------------------------------------------------------

typedef short bf16x8 __attribute__((ext_vector_type(8)));
typedef float f32x4 __attribute__((ext_vector_type(4)));

__device__ __forceinline__ unsigned f2bf(float f) {  // RNE fp32->bf16 bits
  unsigned u = __float_as_uint(f);
  u += 0x7fff + ((u >> 16) & 1);
  return u >> 16;
}
__device__ __forceinline__ float bf2f(unsigned s) {
  return __uint_as_float(s << 16);
}

// ---------------- CSR build ----------------
__global__ void k_count(const int* __restrict__ src, const int* __restrict__ dst,
                        unsigned* __restrict__ deg, unsigned* __restrict__ cnt, int E) {
  int i = blockIdx.x * blockDim.x + threadIdx.x;
  if (i < E) {
    atomicAdd(&deg[src[i]], 1u);
    atomicAdd(&cnt[dst[i]], 1u);
  }
}

__global__ void k_dinv(const unsigned* __restrict__ deg, float* __restrict__ dinv, int N) {
  int i = blockIdx.x * blockDim.x + threadIdx.x;
  if (i < N) {
    unsigned d = deg[i];
    dinv[i] = d ? rsqrtf((float)d) : 0.0f;
  }
}

__global__ __launch_bounds__(256) void k_scan1(const unsigned* __restrict__ cnt,
                                               unsigned* __restrict__ btot, int N) {
  __shared__ unsigned s[256];
  int b = blockIdx.x, t = threadIdx.x;
  int base = b * 1024;
  unsigned sum = 0;
  for (int i = t; i < 1024; i += 256) {
    int idx = base + i;
    sum += (idx < N) ? cnt[idx] : 0u;
  }
  s[t] = sum;
  __syncthreads();
  for (int off = 128; off > 0; off >>= 1) {
    if (t < off) s[t] += s[t + off];
    __syncthreads();
  }
  if (t == 0) btot[b] = s[0];
}

__global__ __launch_bounds__(256) void k_scan2(unsigned* __restrict__ btot,
                                               unsigned* __restrict__ rowstart,
                                               int NB, int N, int E) {
  __shared__ unsigned s[256];
  int t = threadIdx.x;
  s[t] = (t < NB) ? btot[t] : 0u;
  __syncthreads();
  if (t == 0) {
    unsigned acc = 0;
    for (int i = 0; i < NB; i++) { unsigned v = s[i]; s[i] = acc; acc += v; }
  }
  __syncthreads();
  if (t < NB) btot[t] = s[t];
  if (t == 0) rowstart[N] = (unsigned)E;
}

__global__ __launch_bounds__(256) void k_scan3(const unsigned* __restrict__ cnt,
                                               const unsigned* __restrict__ btot,
                                               unsigned* __restrict__ rowstart,
                                               unsigned* __restrict__ cursor, int N) {
  __shared__ unsigned ssum[256];
  int b = blockIdx.x, t = threadIdx.x;
  int base = b * 1024 + t * 4;
  unsigned v0 = 0, v1 = 0, v2 = 0, v3 = 0;
  if (base + 0 < N) v0 = cnt[base + 0];
  if (base + 1 < N) v1 = cnt[base + 1];
  if (base + 2 < N) v2 = cnt[base + 2];
  if (base + 3 < N) v3 = cnt[base + 3];
  ssum[t] = v0 + v1 + v2 + v3;
  __syncthreads();
  for (int off = 1; off < 256; off <<= 1) {
    unsigned add = (t >= off) ? ssum[t - off] : 0u;
    __syncthreads();
    ssum[t] += add;
    __syncthreads();
  }
  unsigned texcl = ((t == 0) ? 0u : ssum[t - 1]) + btot[b];
  unsigned r0 = texcl, r1 = r0 + v0, r2 = r1 + v1, r3 = r2 + v2;
  if (base + 0 < N) { rowstart[base + 0] = r0; cursor[base + 0] = r0; }
  if (base + 1 < N) { rowstart[base + 1] = r1; cursor[base + 1] = r1; }
  if (base + 2 < N) { rowstart[base + 2] = r2; cursor[base + 2] = r2; }
  if (base + 3 < N) { rowstart[base + 3] = r3; cursor[base + 3] = r3; }
}

__global__ void k_fill(const int* __restrict__ src, const int* __restrict__ dst,
                       const float* __restrict__ dinv, unsigned* __restrict__ cursor,
                       int2* __restrict__ er, int E) {
  int e = blockIdx.x * blockDim.x + threadIdx.x;
  if (e >= E) return;
  int s = src[e], d = dst[e];
  unsigned pos = atomicAdd(&cursor[d], 1u);
  er[pos] = make_int2(s, __float_as_int(dinv[s]));
}

// ---------------- prep kernels ----------------
__global__ void k_prep_xb(const float* __restrict__ x, unsigned short* __restrict__ xb, int N) {
  int idx = blockIdx.x * blockDim.x + threadIdx.x;
  int n = idx >> 6, p = idx & 63;
  if (n >= N) return;
  int c = p * 2;
  if (c < 58) {
    unsigned lo = f2bf(x[(size_t)n * 58 + c]);
    unsigned hi = f2bf(x[(size_t)n * 58 + c + 1]);
    *(unsigned*)(xb + (size_t)n * 128 + c) = lo | (hi << 16);
  } else if (c >= 116) {
    *(unsigned*)(xb + (size_t)n * 128 + c) = 0;
  }
}

__global__ void k_prep_w1(const float* __restrict__ W1, unsigned short* __restrict__ Wt1) {
  int idx = blockIdx.x * blockDim.x + threadIdx.x;
  int j = idx >> 6, p = idx & 63;
  if (j >= 304) return;
  int k = p * 2;
  unsigned v[2];
#pragma unroll
  for (int q = 0; q < 2; q++) {
    int kk = k + q;
    float f = 0.0f;
    if (j < 300) {
      if (kk < 58) f = W1[kk * 300 + j];
      else if (kk < 116) f = W1[17400 + (kk - 58) * 300 + j];
    }
    v[q] = f2bf(f);
  }
  *(unsigned*)(Wt1 + j * 128 + k) = v[0] | (v[1] << 16);
}

__global__ void k_prep_w2(const float* __restrict__ W2, unsigned short* __restrict__ Wt2) {
  int idx = blockIdx.x * blockDim.x + threadIdx.x;
  int r = idx / 160, p = idx % 160;
  if (r >= 208) return;
  int k = p * 2;
  unsigned v[2];
#pragma unroll
  for (int q = 0; q < 2; q++) {
    int kk = k + q;
    float f = 0.0f;
    if (kk < 300) {
      if (r < 100) f = W2[30000 + kk * 100 + r];
      else if (r >= 104 && r < 204) f = W2[kk * 100 + (r - 104)];
    }
    v[q] = f2bf(f);
  }
  *(unsigned*)(Wt2 + r * 320 + k) = v[0] | (v[1] << 16);
}

// ---------------- gathers (x4 MLP-unrolled) ----------------
__global__ __launch_bounds__(256) void k_gather58(
    const unsigned* __restrict__ rowstart, const int2* __restrict__ er,
    const float* __restrict__ dinv, unsigned short* __restrict__ xb, int N) {
  int wid = (blockIdx.x * blockDim.x + threadIdx.x) >> 6;
  if (wid >= N) return;
  int lane = threadIdx.x & 63;
  int c0 = lane * 2;
  if (c0 >= 58) return;
  unsigned s0 = rowstart[wid], s1 = rowstart[wid + 1];
  float a0 = 0.f, a1 = 0.f, b0 = 0.f, b1 = 0.f;
  float c0a = 0.f, c1a = 0.f, d0 = 0.f, d1 = 0.f;
  unsigned e = s0;
  for (; e + 4 <= s1; e += 4) {
    int2 r0 = er[e], r1 = er[e + 1], r2 = er[e + 2], r3 = er[e + 3];
    unsigned v0 = *(const unsigned*)(xb + (size_t)r0.x * 128 + c0);
    unsigned v1 = *(const unsigned*)(xb + (size_t)r1.x * 128 + c0);
    unsigned v2 = *(const unsigned*)(xb + (size_t)r2.x * 128 + c0);
    unsigned v3 = *(const unsigned*)(xb + (size_t)r3.x * 128 + c0);
    float w0 = __int_as_float(r0.y), w1 = __int_as_float(r1.y);
    float w2 = __int_as_float(r2.y), w3 = __int_as_float(r3.y);
    a0 += w0 * bf2f(v0 & 0xffffu); a1 += w0 * bf2f(v0 >> 16);
    b0 += w1 * bf2f(v1 & 0xffffu); b1 += w1 * bf2f(v1 >> 16);
    c0a += w2 * bf2f(v2 & 0xffffu); c1a += w2 * bf2f(v2 >> 16);
    d0 += w3 * bf2f(v3 & 0xffffu); d1 += w3 * bf2f(v3 >> 16);
  }
  for (; e < s1; ++e) {
    int2 r = er[e];
    float w = __int_as_float(r.y);
    unsigned v = *(const unsigned*)(xb + (size_t)r.x * 128 + c0);
    a0 += w * bf2f(v & 0xffffu); a1 += w * bf2f(v >> 16);
  }
  float dd = -dinv[wid];
  float p0 = dd * ((a0 + b0) + (c0a + d0));
  float p1 = dd * ((a1 + b1) + (c1a + d1));
  *(unsigned*)(xb + (size_t)wid * 128 + 58 + c0) = f2bf(p0) | (f2bf(p1) << 16);
}

// layer2 tail fused: p2 = prop(g2); h2 = relu(a2+p2+b2); a3,g3 = h2@W30/W31
// ga2b row: cols 0..99 = g2, 104..203 = a2 (stride 208)
__global__ __launch_bounds__(256) void k_gather_l2(
    const unsigned* __restrict__ rowstart, const int2* __restrict__ er,
    const float* __restrict__ dinv, const unsigned short* __restrict__ ga2b,
    const float* __restrict__ b2, const float* __restrict__ W30,
    const float* __restrict__ W31, const float* __restrict__ b3,
    float* __restrict__ a3, float* __restrict__ g3, int N) {
  int wid = (blockIdx.x * blockDim.x + threadIdx.x) >> 6;
  if (wid >= N) return;
  int lane = threadIdx.x & 63;
  int c0 = lane * 2;
  bool act = c0 < 100;
  unsigned s0 = rowstart[wid], s1 = rowstart[wid + 1];
  float aa = 0.f, gg = 0.f;
  if (act) {
    float a0 = 0.f, a1 = 0.f, b0 = 0.f, b1 = 0.f;
    float c0a = 0.f, c1a = 0.f, d0 = 0.f, d1 = 0.f;
    unsigned e = s0;
    for (; e + 4 <= s1; e += 4) {
      int2 r0 = er[e], r1 = er[e + 1], r2 = er[e + 2], r3 = er[e + 3];
      unsigned v0 = *(const unsigned*)(ga2b + (size_t)r0.x * 208 + c0);
      unsigned v1 = *(const unsigned*)(ga2b + (size_t)r1.x * 208 + c0);
      unsigned v2 = *(const unsigned*)(ga2b + (size_t)r2.x * 208 + c0);
      unsigned v3 = *(const unsigned*)(ga2b + (size_t)r3.x * 208 + c0);
      float w0 = __int_as_float(r0.y), w1 = __int_as_float(r1.y);
      float w2 = __int_as_float(r2.y), w3 = __int_as_float(r3.y);
      a0 += w0 * bf2f(v0 & 0xffffu); a1 += w0 * bf2f(v0 >> 16);
      b0 += w1 * bf2f(v1 & 0xffffu); b1 += w1 * bf2f(v1 >> 16);
      c0a += w2 * bf2f(v2 & 0xffffu); c1a += w2 * bf2f(v2 >> 16);
      d0 += w3 * bf2f(v3 & 0xffffu); d1 += w3 * bf2f(v3 >> 16);
    }
    for (; e < s1; ++e) {
      int2 r = er[e];
      float w = __int_as_float(r.y);
      unsigned v = *(const unsigned*)(ga2b + (size_t)r.x * 208 + c0);
      a0 += w * bf2f(v & 0xffffu); a1 += w * bf2f(v >> 16);
    }
    float dd = -dinv[wid];
    float p0 = dd * ((a0 + b0) + (c0a + d0));
    float p1 = dd * ((a1 + b1) + (c1a + d1));
    unsigned av = *(const unsigned*)(ga2b + (size_t)wid * 208 + 104 + c0);
    float h0 = fmaxf(bf2f(av & 0xffffu) + p0 + b2[c0], 0.f);
    float h1 = fmaxf(bf2f(av >> 16) + p1 + b2[c0 + 1], 0.f);
    aa = h0 * W30[c0] + h1 * W30[c0 + 1];
    gg = h0 * W31[c0] + h1 * W31[c0 + 1];
  }
#pragma unroll
  for (int off = 32; off > 0; off >>= 1) {
    aa += __shfl_xor(aa, off);
    gg += __shfl_xor(gg, off);
  }
  if (lane == 0) {
    a3[wid] = aa + b3[0];
    g3[wid] = gg;
  }
}

__global__ void k_gather1(const unsigned* __restrict__ rowstart, const int2* __restrict__ er,
                          const float* __restrict__ dinv, const float* __restrict__ g3,
                          const float* __restrict__ a3, float* __restrict__ out, int N) {
  int n = blockIdx.x * blockDim.x + threadIdx.x;
  if (n >= N) return;
  unsigned s0 = rowstart[n], s1 = rowstart[n + 1];
  float a = 0.f, b = 0.f, c = 0.f, d = 0.f;
  unsigned e = s0;
  for (; e + 4 <= s1; e += 4) {
    int2 r0 = er[e], r1 = er[e + 1], r2 = er[e + 2], r3 = er[e + 3];
    float g0 = g3[r0.x], g1 = g3[r1.x], g2v = g3[r2.x], g3v = g3[r3.x];
    a += __int_as_float(r0.y) * g0;
    b += __int_as_float(r1.y) * g1;
    c += __int_as_float(r2.y) * g2v;
    d += __int_as_float(r3.y) * g3v;
  }
  for (; e < s1; ++e) {
    int2 r = er[e];
    a += __int_as_float(r.y) * g3[r.x];
  }
  out[n] = a3[n] - dinv[n] * ((a + b) + (c + d));
}

// ---------------- MFMA matmuls (LDS-staged coalesced C-writes) ----------------
// h1b = relu(xb @ Wt1^T + b1). 4 waves x 32 rows, K=128. Columns in two
// 160-wide halves staged per-wave in LDS, copied as uint4 (320 B runs/row).
// LDS 40KB -> 4 blk/CU; (256,4) caps VGPR at 128 (need ~70) -> no spill.
__global__ __launch_bounds__(256, 4) void k_mm1_mfma(
    const unsigned short* __restrict__ xb, const unsigned short* __restrict__ Wt1,
    const float* __restrict__ b1, unsigned short* __restrict__ h1b) {
  __shared__ unsigned short tile[4][32][160];  // 40 KB
  int wv = threadIdx.x >> 6, lane = threadIdx.x & 63;
  int rbase = blockIdx.x * 128 + wv * 32;
  int lr = lane & 15, lk = (lane >> 4) * 8;
  bf16x8 a[2][4];
#pragma unroll
  for (int rt = 0; rt < 2; rt++)
#pragma unroll
    for (int s = 0; s < 4; s++)
      a[rt][s] = *(const bf16x8*)(xb + (size_t)(rbase + rt * 16 + lr) * 128 + s * 32 + lk);
#pragma unroll
  for (int half = 0; half < 2; half++) {
    int j0 = half * 10, j1 = half ? 19 : 10;
    for (int j = j0; j < j1; j++) {
      int c = j * 16 + lr;
      f32x4 acc0 = {0.f, 0.f, 0.f, 0.f}, acc1 = {0.f, 0.f, 0.f, 0.f};
#pragma unroll
      for (int s = 0; s < 4; s++) {
        bf16x8 b = *(const bf16x8*)(Wt1 + (size_t)c * 128 + s * 32 + lk);
        acc0 = __builtin_amdgcn_mfma_f32_16x16x32_bf16(a[0][s], b, acc0, 0, 0, 0);
        acc1 = __builtin_amdgcn_mfma_f32_16x16x32_bf16(a[1][s], b, acc1, 0, 0, 0);
      }
      float bias = (c < 300) ? b1[c] : 0.0f;
      int lc = c - half * 160;
      int r0 = (lane >> 4) * 4;
#pragma unroll
      for (int i = 0; i < 4; i++) {
        unsigned short v0 = (c < 300) ? (unsigned short)f2bf(fmaxf(acc0[i] + bias, 0.f)) : 0;
        unsigned short v1 = (c < 300) ? (unsigned short)f2bf(fmaxf(acc1[i] + bias, 0.f)) : 0;
        tile[wv][r0 + i][lc] = v0;
        tile[wv][r0 + 16 + i][lc] = v1;
      }
    }
    if (half == 1) {  // zero K-pad cols 304..319 (local 144..159)
      for (int idx = lane; idx < 32 * 16; idx += 64)
        tile[wv][idx >> 4][144 + (idx & 15)] = 0;
    }
    // copy wave tile: 32 rows x 320 B at global row stride 640 B
    for (int idx = lane; idx < 32 * 20; idx += 64) {
      int row = idx / 20, q = idx % 20;
      *(uint4*)(h1b + (size_t)(rbase + row) * 320 + half * 160 + q * 8) =
          *(const uint4*)&tile[wv][row][q * 8];
    }
  }
}

// ga2b = h1b @ Wt2^T. K=320 (10 steps), 13 col-tiles. Wave tile 32x208 staged
// in LDS, copied as one 13312 B contiguous span (rows consecutive).
// LDS 52KB -> 3 blk/CU; (256,3) caps VGPR at ~170 (A-frags alone need 80;
// round-5's (256) default gave 68 -> spill/remat = 81us latency disaster).
__global__ __launch_bounds__(256, 3) void k_mm2_mfma(
    const unsigned short* __restrict__ h1b, const unsigned short* __restrict__ Wt2,
    unsigned short* __restrict__ ga2b) {
  __shared__ unsigned short tile[4][32][208];  // 52 KB
  int wv = threadIdx.x >> 6, lane = threadIdx.x & 63;
  int rbase = blockIdx.x * 128 + wv * 32;
  int lr = lane & 15, lk = (lane >> 4) * 8;
  bf16x8 a[2][10];
#pragma unroll
  for (int rt = 0; rt < 2; rt++)
#pragma unroll
    for (int s = 0; s < 10; s++)
      a[rt][s] = *(const bf16x8*)(h1b + (size_t)(rbase + rt * 16 + lr) * 320 + s * 32 + lk);
  for (int j = 0; j < 13; j++) {
    int c = j * 16 + lr;
    f32x4 acc0 = {0.f, 0.f, 0.f, 0.f}, acc1 = {0.f, 0.f, 0.f, 0.f};
#pragma unroll
    for (int s = 0; s < 10; s++) {
      bf16x8 b = *(const bf16x8*)(Wt2 + (size_t)c * 320 + s * 32 + lk);
      acc0 = __builtin_amdgcn_mfma_f32_16x16x32_bf16(a[0][s], b, acc0, 0, 0, 0);
      acc1 = __builtin_amdgcn_mfma_f32_16x16x32_bf16(a[1][s], b, acc1, 0, 0, 0);
    }
    int r0 = (lane >> 4) * 4;
#pragma unroll
    for (int i = 0; i < 4; i++) {
      tile[wv][r0 + i][c] = (unsigned short)f2bf(acc0[i]);
      tile[wv][r0 + 16 + i][c] = (unsigned short)f2bf(acc1[i]);
    }
  }
  // wave tile = rows rbase..rbase+31, 208 cols -> 13312 contiguous bytes
  const uint4* lsrc = (const uint4*)&tile[wv][0][0];
  uint4* gdst = (uint4*)(ga2b + (size_t)rbase * 208);
  for (int idx = lane; idx < 832; idx += 64) gdst[idx] = lsrc[idx];
}

// ---------------- launch ----------------
extern "C" void kernel_launch(void* const* d_in, const int* in_sizes, int n_in,
                              void* d_out, int out_size, void* d_ws, size_t ws_size,
                              hipStream_t stream) {
  const float* x  = (const float*)d_in[0];
  const int*   ei = (const int*)d_in[1];
  const float* W1 = (const float*)d_in[2];  // [2][58][300]
  const float* b1 = (const float*)d_in[3];
  const float* W2 = (const float*)d_in[4];  // [2][300][100]
  const float* b2 = (const float*)d_in[5];
  const float* W3 = (const float*)d_in[6];  // [2][100][1]
  const float* b3 = (const float*)d_in[7];
  float* out = (float*)d_out;

  const int N = in_sizes[0] / 58;            // 100000
  const int E = in_sizes[1] / 2;             // 800000
  const int NR = (N + 127) & ~127;           // 100096
  const int NB = (N + 1023) / 1024;
  const int* src = ei;
  const int* dst = ei + E;

  char* ws = (char*)d_ws;
  size_t off = 0;
  auto alloc = [&](size_t bytes) -> void* {
    void* p = ws + off;
    off += (bytes + 255) & ~(size_t)255;
    return p;
  };
  unsigned* deg      = (unsigned*)alloc((size_t)2 * N * 4);
  unsigned* cnt      = deg + N;
  float*    dinv     = (float*)alloc((size_t)N * 4);
  unsigned* rowstart = (unsigned*)alloc((size_t)(N + 1) * 4);
  unsigned* cursor   = (unsigned*)alloc((size_t)N * 4);
  unsigned* btot     = (unsigned*)alloc((size_t)256 * 4);
  int2*     er       = (int2*)alloc((size_t)E * 8);
  unsigned short* xb   = (unsigned short*)alloc((size_t)NR * 128 * 2);
  unsigned short* Wt1  = (unsigned short*)alloc((size_t)304 * 128 * 2);
  unsigned short* Wt2  = (unsigned short*)alloc((size_t)208 * 320 * 2);
  unsigned short* h1b  = (unsigned short*)alloc((size_t)NR * 320 * 2);
  unsigned short* ga2b = (unsigned short*)alloc((size_t)NR * 208 * 2);
  float* a3 = (float*)alloc((size_t)N * 4);
  float* g3 = (float*)alloc((size_t)N * 4);

  // --- CSR + dinv ---
  hipMemsetAsync(deg, 0, (size_t)2 * N * 4, stream);
  k_count<<<(E + 255) / 256, 256, 0, stream>>>(src, dst, deg, cnt, E);
  k_dinv<<<(N + 255) / 256, 256, 0, stream>>>(deg, dinv, N);
  k_scan1<<<NB, 256, 0, stream>>>(cnt, btot, N);
  k_scan2<<<1, 256, 0, stream>>>(btot, rowstart, NB, N, E);
  k_scan3<<<NB, 256, 0, stream>>>(cnt, btot, rowstart, cursor, N);
  k_fill<<<(E + 255) / 256, 256, 0, stream>>>(src, dst, dinv, cursor, er, E);

  // --- preps ---
  k_prep_w1<<<(304 * 64 + 255) / 256, 256, 0, stream>>>(W1, Wt1);
  k_prep_w2<<<(208 * 160 + 255) / 256, 256, 0, stream>>>(W2, Wt2);
  k_prep_xb<<<((size_t)N * 64 + 255) / 256, 256, 0, stream>>>(x, xb, N);

  // --- layer 1 ---
  k_gather58<<<(N + 3) / 4, 256, 0, stream>>>(rowstart, er, dinv, xb, N);
  k_mm1_mfma<<<NR / 128, 256, 0, stream>>>(xb, Wt1, b1, h1b);

  // --- layer 2 ---
  k_mm2_mfma<<<NR / 128, 256, 0, stream>>>(h1b, Wt2, ga2b);
  k_gather_l2<<<(N + 3) / 4, 256, 0, stream>>>(rowstart, er, dinv, ga2b,
                                               b2, W3, W3 + 100, b3, a3, g3, N);

  // --- layer 3 ---
  k_gather1<<<(N + 255) / 256, 256, 0, stream>>>(rowstart, er, dinv, g3, a3, out, N);
}